// Round 2
// baseline (2879.260 us; speedup 1.0000x reference)
//
#include <hip/hip_runtime.h>
#include <hip/hip_bf16.h>
#include <cstddef>

#define BSZ 16
#define NPT 1024
#define KNN 30
#define TKR 9
#define FLT_BIG 3.402823466e+38f
#define DBL_BIG 1.0e300

__device__ __forceinline__ float gelu_f(float x) {
    return 0.5f * x * (1.0f + erff(x * 0.7071067811865476f));
}

// ---------------------------------------------------------------------------
// 1. transpose x [B,3,N] -> pts [B,N,3]
// ---------------------------------------------------------------------------
__global__ __launch_bounds__(256) void transpose_kernel(
    const float* __restrict__ x, float* __restrict__ pts) {
    int t = blockIdx.x * 256 + threadIdx.x;
    if (t >= BSZ * NPT) return;
    int b = t >> 10, n = t & 1023;
    const float* xp = x + (size_t)b * 3 * NPT;
    pts[t * 3 + 0] = xp[n];
    pts[t * 3 + 1] = xp[NPT + n];
    pts[t * 3 + 2] = xp[2 * NPT + n];
}

// ---------------------------------------------------------------------------
// 2. kNN in FP64: top-30 of negd = 2*inner - |p|^2 - |q|^2 (descending,
//    ties -> lower index). fp64 makes the ordering exact (products of fp32
//    are exact in fp64; 1e-16 rounding << 1e-2 distance gaps), matching the
//    fp64 gold reference's top_k selection.
// ---------------------------------------------------------------------------
__global__ __launch_bounds__(256) void knn_kernel(
    const float* __restrict__ pts, int* __restrict__ idx) {
    __shared__ double d[NPT];
    __shared__ double rv[256];
    __shared__ int ri[256];
    int bn_ = blockIdx.x;
    int b = bn_ >> 10;
    int tid = threadIdx.x;
    double px = (double)pts[(size_t)bn_ * 3 + 0];
    double py = (double)pts[(size_t)bn_ * 3 + 1];
    double pz = (double)pts[(size_t)bn_ * 3 + 2];
    double xn = px * px + py * py + pz * pz;
    const float* pb = pts + (size_t)(b << 10) * 3;
    for (int m = tid; m < NPT; m += 256) {
        double qx = (double)pb[m * 3 + 0];
        double qy = (double)pb[m * 3 + 1];
        double qz = (double)pb[m * 3 + 2];
        double inner = px * qx + py * qy + pz * qz;
        double xm = qx * qx + qy * qy + qz * qz;
        d[m] = 2.0 * inner - xn - xm;
    }
    __syncthreads();
    int* op = idx + (size_t)bn_ * KNN;
    for (int it = 0; it < KNN; it++) {
        double bv = -DBL_BIG;
        int bi = 0x7fffffff;
        for (int m = tid; m < NPT; m += 256) {
            double v = d[m];
            if (v > bv) { bv = v; bi = m; }   // strict > keeps lowest idx in-thread
        }
        rv[tid] = bv; ri[tid] = bi;
        __syncthreads();
        for (int s = 128; s > 0; s >>= 1) {
            if (tid < s) {
                double ov = rv[tid + s]; int oi = ri[tid + s];
                if (ov > rv[tid] || (ov == rv[tid] && oi < ri[tid])) {
                    rv[tid] = ov; ri[tid] = oi;
                }
            }
            __syncthreads();
        }
        if (tid == 0) {
            op[it] = ri[0];
            d[ri[0]] = -DBL_BIG;
        }
        __syncthreads();
    }
}

// ---------------------------------------------------------------------------
// 3. basis: Fourier feats -> sparsemax(w) -> P[k,t] per point. Block = 64.
// ---------------------------------------------------------------------------
__global__ __launch_bounds__(64) void basis_kernel(
    const float* __restrict__ pts, const int* __restrict__ idx,
    const float* __restrict__ B_ff, const float* __restrict__ mlp_W,
    const float* __restrict__ permx, float* __restrict__ P) {
    __shared__ float npt[KNN * 3];
    __shared__ float feats[7 * KNN];
    __shared__ float sc[64];
    __shared__ float zl[16];
    __shared__ float w[16];
    int bn_ = blockIdx.x;
    int b = bn_ >> 10;
    int tid = threadIdx.x;
    const int* ip = idx + (size_t)bn_ * KNN;
    if (tid < KNN) {
        int m = ip[tid];
        const float* q = pts + ((size_t)(b << 10) + m) * 3;
        npt[tid * 3 + 0] = q[0];
        npt[tid * 3 + 1] = q[1];
        npt[tid * 3 + 2] = q[2];
    }
    __syncthreads();
    if (tid < KNN) {
        float sx = npt[0], sy = npt[1], sz = npt[2];
        float rx = npt[tid * 3 + 0] - sx;
        float ry = npt[tid * 3 + 1] - sy;
        float rz = npt[tid * 3 + 2] - sz;
        float sq = rx * rx + ry * ry + rz * rz;
        float dist = (sq > 0.0f) ? sqrtf(sq) : 0.0f;
        feats[tid * 7 + 0] = sx;
        feats[tid * 7 + 1] = sy;
        feats[tid * 7 + 2] = sz;
        feats[tid * 7 + 3] = rx;
        feats[tid * 7 + 4] = ry;
        feats[tid * 7 + 5] = rz;
        feats[tid * 7 + 6] = dist;
    }
    __syncthreads();
    if (tid < 32) {
        float acc = 0.0f;
        for (int i = 0; i < 7 * KNN; i++) acc += feats[i] * B_ff[i * 32 + tid];
        float ffv = 6.283185307179586f * acc;
        sc[tid] = sinf(ffv);
        sc[tid + 32] = cosf(ffv);
    }
    __syncthreads();
    if (tid < 16) {
        float acc = 0.0f;
        for (int j = 0; j < 64; j++) acc += sc[j] * mlp_W[j * 16 + tid];
        zl[tid] = acc;
    }
    __syncthreads();
    if (tid == 0) {
        float zs[16];
        for (int i = 0; i < 16; i++) zs[i] = zl[i];
        for (int i = 1; i < 16; i++) {          // insertion sort descending
            float key = zs[i]; int j = i - 1;
            while (j >= 0 && zs[j] < key) { zs[j + 1] = zs[j]; j--; }
            zs[j + 1] = key;
        }
        float cs = 0.0f, csarr[16];
        int cnt = 0;
        for (int j = 0; j < 16; j++) {
            cs += zs[j];
            csarr[j] = cs;
            if (1.0f + (float)(j + 1) * zs[j] > cs) cnt++;
        }
        float tau = (csarr[cnt - 1] - 1.0f) / (float)cnt;
        for (int i = 0; i < 16; i++) w[i] = fmaxf(zl[i] - tau, 0.0f);
    }
    __syncthreads();
    float* Pp = P + (size_t)bn_ * (KNN * TKR);
    for (int e = tid; e < KNN * TKR; e += 64) {
        int k = e / TKR, t = e - TKR * k;
        float acc = 0.0f;
        for (int i = 0; i < 16; i++) acc += w[i] * permx[(i * KNN + k) * TKR + t];
        Pp[e] = acc;
    }
}

// ---------------------------------------------------------------------------
// 4. paiconv: block per point. agg[t,c] = sum_k nb[k,c]*P[k,t];
//    out = gelu(agg@W + b + self@S)
// ---------------------------------------------------------------------------
template <int CIN, int COUT>
__global__ __launch_bounds__(256) void paiconv_kernel(
    const float* __restrict__ ft, int ftst,
    const float* __restrict__ P, const int* __restrict__ idx,
    const float* __restrict__ W, const float* __restrict__ bias,
    const float* __restrict__ S,
    float* __restrict__ out, int outst) {
    __shared__ float sP[KNN * TKR];
    __shared__ float sSelf[CIN];
    __shared__ float sNb[KNN * CIN];
    __shared__ float sAgg[TKR * CIN];
    int bn_ = blockIdx.x;
    int b = bn_ >> 10;
    int tid = threadIdx.x;
    const int* ip = idx + (size_t)bn_ * KNN;
    for (int e = tid; e < KNN * TKR; e += 256) sP[e] = P[(size_t)bn_ * (KNN * TKR) + e];
    const float* selfrow = ft + (size_t)bn_ * ftst;
    for (int c = tid; c < CIN; c += 256) sSelf[c] = selfrow[c];
    for (int e = tid; e < KNN * CIN; e += 256) {
        int k = e / CIN, c = e - k * CIN;
        int m = ip[k];
        sNb[e] = ft[((size_t)(b << 10) + m) * ftst + c];
    }
    __syncthreads();
    for (int e = tid; e < TKR * CIN; e += 256) {
        int t = e / CIN, c = e - t * CIN;
        float acc = 0.0f;
        for (int k = 0; k < KNN; k++) acc += sNb[k * CIN + c] * sP[k * TKR + t];
        sAgg[e] = acc;
    }
    __syncthreads();
    for (int co = tid; co < COUT; co += 256) {
        float acc = bias[co];
        for (int j = 0; j < TKR * CIN; j++) acc += sAgg[j] * W[(size_t)j * COUT + co];
        for (int c = 0; c < CIN; c++) acc += sSelf[c] * S[(size_t)c * COUT + co];
        out[(size_t)bn_ * outst + co] = gelu_f(acc);
    }
}

// ---------------------------------------------------------------------------
// 5. conv5 GEMM: C[M,N] = A[M,K] @ B[K,N]; M=16384, K=512, N=1024
// ---------------------------------------------------------------------------
__global__ __launch_bounds__(256) void gemm_conv5(
    const float* __restrict__ A, const float* __restrict__ B, float* __restrict__ C,
    int M, int N, int Kd) {
    __shared__ float As[16][64];
    __shared__ float Bs[16][64];
    int m0 = blockIdx.y * 64, n0 = blockIdx.x * 64;
    int tid = threadIdx.x;
    int tx = tid & 15, ty = tid >> 4;
    float acc[4][4] = {};
    for (int k0 = 0; k0 < Kd; k0 += 16) {
        {
            int m = tid >> 2;
            int kk = (tid & 3) * 4;
            const float4 v = *(const float4*)(A + (size_t)(m0 + m) * Kd + k0 + kk);
            As[kk + 0][m] = v.x; As[kk + 1][m] = v.y;
            As[kk + 2][m] = v.z; As[kk + 3][m] = v.w;
        }
        {
            int n = tid & 63, kk0 = tid >> 6;
            for (int i = 0; i < 4; i++) {
                int kk = kk0 + i * 4;
                Bs[kk][n] = B[(size_t)(k0 + kk) * N + n0 + n];
            }
        }
        __syncthreads();
        for (int kk = 0; kk < 16; kk++) {
            float a[4], bv[4];
            for (int r = 0; r < 4; r++) a[r] = As[kk][ty * 4 + r];
            for (int c = 0; c < 4; c++) bv[c] = Bs[kk][tx * 4 + c];
            for (int r = 0; r < 4; r++)
                for (int c = 0; c < 4; c++) acc[r][c] += a[r] * bv[c];
        }
        __syncthreads();
    }
    for (int r = 0; r < 4; r++) {
        int m = m0 + ty * 4 + r;
        float4 v = make_float4(acc[r][0], acc[r][1], acc[r][2], acc[r][3]);
        *(float4*)(C + (size_t)m * N + n0 + tx * 4) = v;
    }
}

// ---------------------------------------------------------------------------
// 6. BN stats over (b,n) per channel e (1024 channels), double accumulation
// ---------------------------------------------------------------------------
__global__ __launch_bounds__(256) void conv5_stats(
    const float* __restrict__ f5, double* __restrict__ sumb, double* __restrict__ sqb) {
    __shared__ double ssum[1024];
    __shared__ double ssq[1024];
    for (int e = threadIdx.x; e < 1024; e += 256) { ssum[e] = 0.0; ssq[e] = 0.0; }
    __syncthreads();
    int p0 = blockIdx.x * 256;
    for (int p = p0; p < p0 + 256; p++) {
        const float* row = f5 + (size_t)p * 1024;
        for (int e = threadIdx.x; e < 1024; e += 256) {
            double v = (double)row[e];
            ssum[e] += v;
            ssq[e] += v * v;
        }
    }
    __syncthreads();
    for (int e = threadIdx.x; e < 1024; e += 256) {
        atomicAdd(&sumb[e], ssum[e]);
        atomicAdd(&sqb[e], ssq[e]);
    }
}

__global__ __launch_bounds__(256) void stats_finalize(
    const double* __restrict__ sumb, const double* __restrict__ sqb,
    const float* __restrict__ g, const float* __restrict__ be,
    float* __restrict__ scaleb, float* __restrict__ shiftb) {
    int e = blockIdx.x * 256 + threadIdx.x;
    if (e >= 1024) return;
    double m = sumb[e] * (1.0 / 16384.0);
    double v = sqb[e] * (1.0 / 16384.0) - m * m;
    float sc = g[e] * (float)(1.0 / sqrt(v + 1e-5));
    scaleb[e] = sc;
    shiftb[e] = be[e] - (float)m * sc;
}

// ---------------------------------------------------------------------------
// 7. pool: h[b, 0:1024] = max_n gelu(bn(f5)); h[b,1024:2048] = mean_n
// ---------------------------------------------------------------------------
__global__ __launch_bounds__(256) void pool_kernel(
    const float* __restrict__ f5, const float* __restrict__ scaleb,
    const float* __restrict__ shiftb, float* __restrict__ h) {
    int b = blockIdx.x >> 4;
    int g = blockIdx.x & 15;
    int e = g * 64 + (threadIdx.x & 63);
    int nlane = threadIdx.x >> 6;
    float sc = scaleb[e], sh = shiftb[e];
    float vmax = -FLT_BIG, vsum = 0.0f;
    for (int n = nlane; n < NPT; n += 4) {
        float v = f5[((size_t)b * NPT + n) * 1024 + e];
        v = gelu_f(v * sc + sh);
        vmax = fmaxf(vmax, v);
        vsum += v;
    }
    __shared__ float smax[256];
    __shared__ float ssum[256];
    smax[threadIdx.x] = vmax;
    ssum[threadIdx.x] = vsum;
    __syncthreads();
    if (nlane == 0) {
        for (int i = 1; i < 4; i++) {
            vmax = fmaxf(vmax, smax[threadIdx.x + 64 * i]);
            vsum += ssum[threadIdx.x + 64 * i];
        }
        h[(size_t)b * 2048 + e] = vmax;
        h[(size_t)b * 2048 + 1024 + e] = vsum * (1.0f / 1024.0f);
    }
}

// ---------------------------------------------------------------------------
// 8. FC head
// ---------------------------------------------------------------------------
__global__ __launch_bounds__(256) void fc_kernel(
    const float* __restrict__ X, const float* __restrict__ W,
    const float* __restrict__ bias, float* __restrict__ Y,
    int Bn, int In, int Out) {
    int tid = blockIdx.x * 256 + threadIdx.x;
    if (tid >= Bn * Out) return;
    int b = tid / Out, j = tid - b * Out;
    const float* x = X + (size_t)b * In;
    float acc = bias ? bias[j] : 0.0f;
    for (int i = 0; i < In; i++) acc += x[i] * W[(size_t)i * Out + j];
    Y[tid] = acc;
}

__global__ __launch_bounds__(256) void bn_gelu_head(
    const float* __restrict__ Xraw, const float* __restrict__ g,
    const float* __restrict__ be, float* __restrict__ Y, int Bn, int F) {
    int j = blockIdx.x * 256 + threadIdx.x;
    if (j >= F) return;
    float m = 0.0f;
    for (int b = 0; b < Bn; b++) m += Xraw[b * F + j];
    m /= (float)Bn;
    float v = 0.0f;
    for (int b = 0; b < Bn; b++) {
        float d = Xraw[b * F + j] - m;
        v += d * d;
    }
    v /= (float)Bn;
    float sc = g[j] * rsqrtf(v + 1e-5f);
    float sh = be[j] - m * sc;
    for (int b = 0; b < Bn; b++) Y[b * F + j] = gelu_f(Xraw[b * F + j] * sc + sh);
}

// ---------------------------------------------------------------------------
extern "C" void kernel_launch(void* const* d_in, const int* in_sizes, int n_in,
                              void* d_out, int out_size, void* d_ws, size_t ws_size,
                              hipStream_t stream) {
    const float* x     = (const float*)d_in[0];
    const float* B_ff  = (const float*)d_in[1];
    const float* mlp_W = (const float*)d_in[2];
    const float* permx = (const float*)d_in[3];
    const float* W1 = (const float*)d_in[4];
    const float* b1 = (const float*)d_in[5];
    const float* S1 = (const float*)d_in[6];
    const float* W2 = (const float*)d_in[7];
    const float* b2 = (const float*)d_in[8];
    const float* S2 = (const float*)d_in[9];
    const float* W3 = (const float*)d_in[10];
    const float* b3 = (const float*)d_in[11];
    const float* S3 = (const float*)d_in[12];
    const float* W4 = (const float*)d_in[13];
    const float* b4 = (const float*)d_in[14];
    const float* S4 = (const float*)d_in[15];
    const float* W5 = (const float*)d_in[16];
    const float* g5 = (const float*)d_in[17];
    const float* be5 = (const float*)d_in[18];
    const float* L1 = (const float*)d_in[19];
    const float* g6 = (const float*)d_in[20];
    const float* be6 = (const float*)d_in[21];
    const float* L2 = (const float*)d_in[22];
    const float* bL2 = (const float*)d_in[23];
    const float* g7 = (const float*)d_in[24];
    const float* be7 = (const float*)d_in[25];
    const float* L3 = (const float*)d_in[26];
    const float* bL3 = (const float*)d_in[27];
    float* outp = (float*)d_out;

    // workspace layout (float units; all offsets 16B-aligned)
    float* ws = (float*)d_ws;
    float* pts   = ws;                        // 49152
    int*   idxb  = (int*)(ws + 49152);        // 491520 ints
    float* Pb    = ws + 540672;               // 4423680
    float* feat  = Pb + 4423680;              // 8388608  (x1|x2|x3|x4 cols 0:512)
    float* f5    = feat + 8388608;            // 16777216
    double* sumd = (double*)(f5 + 16777216);  // 1024 doubles
    double* sqd  = sumd + 1024;               // 1024 doubles
    float* scb   = (float*)(sqd + 1024);      // 1024
    float* shb   = scb + 1024;                // 1024
    float* hb    = shb + 1024;                // 32768
    float* raw1  = hb + 32768;                // 8192
    float* y1    = raw1 + 8192;               // 8192
    float* raw2  = y1 + 8192;                 // 4096
    float* y2    = raw2 + 4096;               // 4096
    size_t need_bytes = (size_t)((y2 + 4096) - ws) * sizeof(float);
    if (ws_size < need_bytes) return;

    const int BN = BSZ * NPT;  // 16384

    transpose_kernel<<<(BN + 255) / 256, 256, 0, stream>>>(x, pts);
    knn_kernel<<<BN, 256, 0, stream>>>(pts, idxb);
    basis_kernel<<<BN, 64, 0, stream>>>(pts, idxb, B_ff, mlp_W, permx, Pb);

    paiconv_kernel<3, 64><<<BN, 256, 0, stream>>>(pts, 3, Pb, idxb, W1, b1, S1, feat + 0, 512);
    paiconv_kernel<64, 64><<<BN, 256, 0, stream>>>(feat + 0, 512, Pb, idxb, W2, b2, S2, feat + 64, 512);
    paiconv_kernel<64, 128><<<BN, 256, 0, stream>>>(feat + 64, 512, Pb, idxb, W3, b3, S3, feat + 128, 512);
    paiconv_kernel<128, 256><<<BN, 256, 0, stream>>>(feat + 128, 512, Pb, idxb, W4, b4, S4, feat + 256, 512);

    gemm_conv5<<<dim3(1024 / 64, BN / 64), 256, 0, stream>>>(feat, W5, f5, BN, 1024, 512);

    hipMemsetAsync(sumd, 0, 2048 * sizeof(double), stream);
    conv5_stats<<<BN / 256, 256, 0, stream>>>(f5, sumd, sqd);
    stats_finalize<<<4, 256, 0, stream>>>(sumd, sqd, g5, be5, scb, shb);
    pool_kernel<<<BSZ * 16, 256, 0, stream>>>(f5, scb, shb, hb);

    fc_kernel<<<(BSZ * 512 + 255) / 256, 256, 0, stream>>>(hb, L1, nullptr, raw1, BSZ, 2048, 512);
    bn_gelu_head<<<2, 256, 0, stream>>>(raw1, g6, be6, y1, BSZ, 512);
    fc_kernel<<<(BSZ * 256 + 255) / 256, 256, 0, stream>>>(y1, L2, bL2, raw2, BSZ, 512, 256);
    bn_gelu_head<<<1, 256, 0, stream>>>(raw2, g7, be7, y2, BSZ, 256);
    fc_kernel<<<(BSZ * 40 + 255) / 256, 256, 0, stream>>>(y2, L3, bL3, outp, BSZ, 256, 40);
}

// Round 4
// 1863.050 us; speedup vs baseline: 1.5455x; 1.5455x over previous
//
#include <hip/hip_runtime.h>
#include <hip/hip_bf16.h>
#include <cstddef>

#define BSZ 16
#define NPT 1024
#define KNN 30
#define TKR 9
#define FLT_BIG 3.402823466e+38f
#define DBL_BIG 1.0e300

__device__ __forceinline__ float gelu_f(float x) {
    return 0.5f * x * (1.0f + erff(x * 0.7071067811865476f));
}

// ---------------------------------------------------------------------------
// 1. transpose x [B,3,N] -> pts [B,N,3]
// ---------------------------------------------------------------------------
__global__ __launch_bounds__(256) void transpose_kernel(
    const float* __restrict__ x, float* __restrict__ pts) {
    int t = blockIdx.x * 256 + threadIdx.x;
    if (t >= BSZ * NPT) return;
    int b = t >> 10, n = t & 1023;
    const float* xp = x + (size_t)b * 3 * NPT;
    pts[t * 3 + 0] = xp[n];
    pts[t * 3 + 1] = xp[NPT + n];
    pts[t * 3 + 2] = xp[2 * NPT + n];
}

// ---------------------------------------------------------------------------
// 2. kNN, REGISTER-ONLY: one wave per point. fp64 distances for exact top_k
//    ordering vs the fp64 gold ref. Each lane owns 16 candidates in
//    registers; 30 iterations of {local scan, shfl_xor butterfly argmax,
//    register kill}. Zero shared state -> bitwise deterministic.
// ---------------------------------------------------------------------------
__global__ __launch_bounds__(64) void knn_kernel(
    const float* __restrict__ pts, int* __restrict__ idx) {
    int lane = threadIdx.x & 63;
    int bn_ = blockIdx.x;
    int b = bn_ >> 10;
    double px = (double)pts[(size_t)bn_ * 3 + 0];
    double py = (double)pts[(size_t)bn_ * 3 + 1];
    double pz = (double)pts[(size_t)bn_ * 3 + 2];
    double xn = px * px + py * py + pz * pz;
    const float* pb = pts + (size_t)(b << 10) * 3;
    int base = lane * 16;
    double cand[16];
    #pragma unroll
    for (int j = 0; j < 16; j++) {
        int m = base + j;
        double qx = (double)pb[m * 3 + 0];
        double qy = (double)pb[m * 3 + 1];
        double qz = (double)pb[m * 3 + 2];
        double inner = px * qx + py * qy + pz * qz;
        double xm = qx * qx + qy * qy + qz * qz;
        cand[j] = 2.0 * inner - xn - xm;
    }
    int* op = idx + (size_t)bn_ * KNN;
    for (int it = 0; it < KNN; it++) {
        double bv = -DBL_BIG;
        int bi = 0x7fffffff;
        #pragma unroll
        for (int j = 0; j < 16; j++) {
            if (cand[j] > bv) { bv = cand[j]; bi = base + j; }  // strict > : lowest idx
        }
        #pragma unroll
        for (int s = 1; s < 64; s <<= 1) {
            double ov = __shfl_xor(bv, s, 64);
            int oi = __shfl_xor(bi, s, 64);
            if (ov > bv || (ov == bv && oi < bi)) { bv = ov; bi = oi; }
        }
        if (lane == 0) op[it] = bi;
        #pragma unroll
        for (int j = 0; j < 16; j++) {
            if (base + j == bi) cand[j] = -DBL_BIG;   // register kill, exact
        }
    }
}

// ---------------------------------------------------------------------------
// 3. basis: Fourier feats -> sparsemax(w) -> P[k,t] per point. Block = 64.
// ---------------------------------------------------------------------------
__global__ __launch_bounds__(64) void basis_kernel(
    const float* __restrict__ pts, const int* __restrict__ idx,
    const float* __restrict__ B_ff, const float* __restrict__ mlp_W,
    const float* __restrict__ permx, float* __restrict__ P) {
    __shared__ float npt[KNN * 3];
    __shared__ float feats[7 * KNN];
    __shared__ float sc[64];
    __shared__ float zl[16];
    __shared__ float w[16];
    int bn_ = blockIdx.x;
    int b = bn_ >> 10;
    int tid = threadIdx.x;
    const int* ip = idx + (size_t)bn_ * KNN;
    if (tid < KNN) {
        int m = ip[tid];
        const float* q = pts + ((size_t)(b << 10) + m) * 3;
        npt[tid * 3 + 0] = q[0];
        npt[tid * 3 + 1] = q[1];
        npt[tid * 3 + 2] = q[2];
    }
    __syncthreads();
    if (tid < KNN) {
        float sx = npt[0], sy = npt[1], sz = npt[2];
        float rx = npt[tid * 3 + 0] - sx;
        float ry = npt[tid * 3 + 1] - sy;
        float rz = npt[tid * 3 + 2] - sz;
        float sq = rx * rx + ry * ry + rz * rz;
        float dist = (sq > 0.0f) ? sqrtf(sq) : 0.0f;
        feats[tid * 7 + 0] = sx;
        feats[tid * 7 + 1] = sy;
        feats[tid * 7 + 2] = sz;
        feats[tid * 7 + 3] = rx;
        feats[tid * 7 + 4] = ry;
        feats[tid * 7 + 5] = rz;
        feats[tid * 7 + 6] = dist;
    }
    __syncthreads();
    if (tid < 32) {
        float acc = 0.0f;
        for (int i = 0; i < 7 * KNN; i++) acc += feats[i] * B_ff[i * 32 + tid];
        float ffv = 6.283185307179586f * acc;
        sc[tid] = sinf(ffv);
        sc[tid + 32] = cosf(ffv);
    }
    __syncthreads();
    if (tid < 16) {
        float acc = 0.0f;
        for (int j = 0; j < 64; j++) acc += sc[j] * mlp_W[j * 16 + tid];
        zl[tid] = acc;
    }
    __syncthreads();
    if (tid == 0) {
        float zs[16];
        for (int i = 0; i < 16; i++) zs[i] = zl[i];
        for (int i = 1; i < 16; i++) {          // insertion sort descending
            float key = zs[i]; int j = i - 1;
            while (j >= 0 && zs[j] < key) { zs[j + 1] = zs[j]; j--; }
            zs[j + 1] = key;
        }
        float cs = 0.0f, csarr[16];
        int cnt = 0;
        for (int j = 0; j < 16; j++) {
            cs += zs[j];
            csarr[j] = cs;
            if (1.0f + (float)(j + 1) * zs[j] > cs) cnt++;
        }
        float tau = (csarr[cnt - 1] - 1.0f) / (float)cnt;
        for (int i = 0; i < 16; i++) w[i] = fmaxf(zl[i] - tau, 0.0f);
    }
    __syncthreads();
    float* Pp = P + (size_t)bn_ * (KNN * TKR);
    for (int e = tid; e < KNN * TKR; e += 64) {
        int k = e / TKR, t = e - TKR * k;
        float acc = 0.0f;
        for (int i = 0; i < 16; i++) acc += w[i] * permx[(i * KNN + k) * TKR + t];
        Pp[e] = acc;
    }
}

// ---------------------------------------------------------------------------
// 4a. agg: Z[bn, t*CIN+c] = sum_k nb[k,c]*P[k,t]; Z[bn, 9*CIN+c] = self[c];
//     zero-pad to kpad. One block per point.
// ---------------------------------------------------------------------------
template <int CIN>
__global__ __launch_bounds__(256) void agg_kernel(
    const float* __restrict__ ft, int ftst,
    const float* __restrict__ P, const int* __restrict__ idx,
    float* __restrict__ Z, int kpad) {
    __shared__ float sP[KNN * TKR];
    __shared__ float sNb[KNN * CIN];
    __shared__ int sIdx[KNN];
    int bn_ = blockIdx.x;
    int b = bn_ >> 10;
    int tid = threadIdx.x;
    if (tid < KNN) sIdx[tid] = idx[(size_t)bn_ * KNN + tid];
    for (int e = tid; e < KNN * TKR; e += 256) sP[e] = P[(size_t)bn_ * (KNN * TKR) + e];
    __syncthreads();
    for (int e = tid; e < KNN * CIN; e += 256) {
        int k = e / CIN, c = e - k * CIN;
        sNb[e] = ft[((size_t)(b << 10) + sIdx[k]) * ftst + c];
    }
    __syncthreads();
    float* zp = Z + (size_t)bn_ * kpad;
    const int KW = TKR * CIN;
    for (int e = tid; e < kpad; e += 256) {
        float v;
        if (e < KW) {
            int t = e / CIN, c = e - t * CIN;
            float acc = 0.0f;
            #pragma unroll
            for (int k = 0; k < KNN; k++) acc += sNb[k * CIN + c] * sP[k * TKR + t];
            v = acc;
        } else if (e < KW + CIN) {
            v = ft[(size_t)bn_ * ftst + (e - KW)];
        } else {
            v = 0.0f;
        }
        zp[e] = v;
    }
}

// ---------------------------------------------------------------------------
// 4b. prep WZ = [W ; S ; 0-pad]  (kpad x N)
// ---------------------------------------------------------------------------
__global__ __launch_bounds__(256) void prep_wz(
    const float* __restrict__ W, const float* __restrict__ S,
    float* __restrict__ WZ, int KW, int KS, int N, int kpad) {
    int t = blockIdx.x * 256 + threadIdx.x;
    if (t >= kpad * N) return;
    int k = t / N, n = t - k * N;
    float v = 0.0f;
    if (k < KW) v = W[(size_t)k * N + n];
    else if (k < KW + KS) v = S[(size_t)(k - KW) * N + n];
    WZ[t] = v;
}

// ---------------------------------------------------------------------------
// 5. fp32 tiled GEMM: C[M,N] = act(A[M,K]@B[K,N] + bias). TM=128, 256 thr,
//    micro-tile 8 rows x NC cols split as 4x4 quadrants at +64 offsets.
// ---------------------------------------------------------------------------
template <int TN, bool GELU, bool HASBIAS>
__global__ __launch_bounds__(256) void gemm_f32(
    const float* __restrict__ A, int lda,
    const float* __restrict__ B, int ldb, int K,
    const float* __restrict__ bias,
    float* __restrict__ C, int ldc) {
    __shared__ float As[16][128];
    __shared__ float Bs[16][TN];
    constexpr int NC = TN / 16;            // 8 (TN=128) or 4 (TN=64)
    int tid = threadIdx.x;
    int tx = tid & 15, ty = tid >> 4;
    int m0 = blockIdx.y * 128, n0 = blockIdx.x * TN;
    float acc[8][NC];
    #pragma unroll
    for (int i = 0; i < 8; i++)
        #pragma unroll
        for (int j = 0; j < NC; j++) acc[i][j] = 0.0f;

    int ar = tid >> 1, ac0 = (tid & 1) * 8;
    const float* aptr = A + (size_t)(m0 + ar) * lda + ac0;

    for (int k0 = 0; k0 < K; k0 += 16) {
        float4 a0 = *(const float4*)(aptr + k0);
        float4 a1 = *(const float4*)(aptr + k0 + 4);
        As[ac0 + 0][ar] = a0.x; As[ac0 + 1][ar] = a0.y;
        As[ac0 + 2][ar] = a0.z; As[ac0 + 3][ar] = a0.w;
        As[ac0 + 4][ar] = a1.x; As[ac0 + 5][ar] = a1.y;
        As[ac0 + 6][ar] = a1.z; As[ac0 + 7][ar] = a1.w;
        if (TN == 128) {
            int r = tid >> 5, c = (tid & 31) * 4;
            const float* bp = B + (size_t)(k0 + r) * ldb + n0 + c;
            float4 b0 = *(const float4*)bp;
            float4 b1 = *(const float4*)(bp + (size_t)8 * ldb);
            *(float4*)&Bs[r][c] = b0;
            *(float4*)&Bs[r + 8][c] = b1;
        } else {
            int r = tid >> 4, c = (tid & 15) * 4;
            float4 b0 = *(const float4*)(B + (size_t)(k0 + r) * ldb + n0 + c);
            *(float4*)&Bs[r][c] = b0;
        }
        __syncthreads();
        #pragma unroll
        for (int kk = 0; kk < 16; kk++) {
            float av[8], bv[NC];
            *(float4*)&av[0] = *(const float4*)&As[kk][ty * 4];
            *(float4*)&av[4] = *(const float4*)&As[kk][64 + ty * 4];
            *(float4*)&bv[0] = *(const float4*)&Bs[kk][tx * 4];
            if (TN == 128) *(float4*)&bv[4] = *(const float4*)&Bs[kk][64 + tx * 4];
            #pragma unroll
            for (int i = 0; i < 8; i++)
                #pragma unroll
                for (int j = 0; j < NC; j++) acc[i][j] += av[i] * bv[j];
        }
        __syncthreads();
    }
    #pragma unroll
    for (int hi = 0; hi < 2; hi++) {
        #pragma unroll
        for (int i = 0; i < 4; i++) {
            int r = m0 + hi * 64 + ty * 4 + i;
            #pragma unroll
            for (int hj = 0; hj < NC / 4; hj++) {
                int c = n0 + hj * 64 + tx * 4;
                float v[4];
                #pragma unroll
                for (int j = 0; j < 4; j++) {
                    float t = acc[hi * 4 + i][hj * 4 + j];
                    if (HASBIAS) t += bias[c + j];
                    if (GELU) t = gelu_f(t);
                    v[j] = t;
                }
                *(float4*)(C + (size_t)r * ldc + c) = *(float4*)v;
            }
        }
    }
}

// ---------------------------------------------------------------------------
// 6. BN stats, two-stage deterministic (NO atomics, NO memset).
//    Stage 1: 256 blocks, each reduces a 64-row slab into per-block partials
//    (register accumulators, fixed order). Stage 2: serial 256-way sum.
// ---------------------------------------------------------------------------
__global__ __launch_bounds__(256) void stats_partial(
    const float* __restrict__ f5, double* __restrict__ partS,
    double* __restrict__ partQ) {
    int tid = threadIdx.x;
    double s[4] = {0.0, 0.0, 0.0, 0.0};
    double q[4] = {0.0, 0.0, 0.0, 0.0};
    int p0 = blockIdx.x * 64;
    for (int p = p0; p < p0 + 64; p++) {
        const float* row = f5 + (size_t)p * 1024;
        #pragma unroll
        for (int k = 0; k < 4; k++) {
            double v = (double)row[tid + 256 * k];
            s[k] += v;
            q[k] += v * v;
        }
    }
    #pragma unroll
    for (int k = 0; k < 4; k++) {
        partS[(size_t)blockIdx.x * 1024 + tid + 256 * k] = s[k];
        partQ[(size_t)blockIdx.x * 1024 + tid + 256 * k] = q[k];
    }
}

__global__ __launch_bounds__(256) void stats_reduce(
    const double* __restrict__ partS, const double* __restrict__ partQ,
    const float* __restrict__ g, const float* __restrict__ be,
    float* __restrict__ scaleb, float* __restrict__ shiftb) {
    int e = blockIdx.x * 256 + threadIdx.x;
    if (e >= 1024) return;
    double s = 0.0, q = 0.0;
    for (int b = 0; b < 256; b++) {
        s += partS[(size_t)b * 1024 + e];
        q += partQ[(size_t)b * 1024 + e];
    }
    double m = s * (1.0 / 16384.0);
    double v = q * (1.0 / 16384.0) - m * m;
    float sc = g[e] * (float)(1.0 / sqrt(v + 1e-5));
    scaleb[e] = sc;
    shiftb[e] = be[e] - (float)m * sc;
}

// ---------------------------------------------------------------------------
// 7. pool: h[b, 0:1024] = max_n gelu(bn(f5)); h[b,1024:2048] = mean_n
// ---------------------------------------------------------------------------
__global__ __launch_bounds__(256) void pool_kernel(
    const float* __restrict__ f5, const float* __restrict__ scaleb,
    const float* __restrict__ shiftb, float* __restrict__ h) {
    int b = blockIdx.x >> 4;
    int g = blockIdx.x & 15;
    int e = g * 64 + (threadIdx.x & 63);
    int nlane = threadIdx.x >> 6;
    float sc = scaleb[e], sh = shiftb[e];
    float vmax = -FLT_BIG;
    double vsum = 0.0;
    for (int n = nlane; n < NPT; n += 4) {
        float v = f5[((size_t)b * NPT + n) * 1024 + e];
        v = gelu_f(v * sc + sh);
        vmax = fmaxf(vmax, v);
        vsum += (double)v;
    }
    __shared__ float smax[256];
    __shared__ double ssum[256];
    smax[threadIdx.x] = vmax;
    ssum[threadIdx.x] = vsum;
    __syncthreads();
    if (nlane == 0) {
        for (int i = 1; i < 4; i++) {
            vmax = fmaxf(vmax, smax[threadIdx.x + 64 * i]);
            vsum += ssum[threadIdx.x + 64 * i];
        }
        h[(size_t)b * 2048 + e] = vmax;
        h[(size_t)b * 2048 + 1024 + e] = (float)(vsum * (1.0 / 1024.0));
    }
}

// ---------------------------------------------------------------------------
// 8. FC head (fp64 accumulation — tiny, protects error margin)
// ---------------------------------------------------------------------------
__global__ __launch_bounds__(256) void fc_kernel(
    const float* __restrict__ X, const float* __restrict__ W,
    const float* __restrict__ bias, float* __restrict__ Y,
    int Bn, int In, int Out) {
    int tid = blockIdx.x * 256 + threadIdx.x;
    if (tid >= Bn * Out) return;
    int b = tid / Out, j = tid - b * Out;
    const float* x = X + (size_t)b * In;
    double acc = bias ? (double)bias[j] : 0.0;
    for (int i = 0; i < In; i++) acc += (double)x[i] * (double)W[(size_t)i * Out + j];
    Y[tid] = (float)acc;
}

__global__ __launch_bounds__(256) void bn_gelu_head(
    const float* __restrict__ Xraw, const float* __restrict__ g,
    const float* __restrict__ be, float* __restrict__ Y, int Bn, int F) {
    int j = blockIdx.x * 256 + threadIdx.x;
    if (j >= F) return;
    double m = 0.0;
    for (int b = 0; b < Bn; b++) m += (double)Xraw[b * F + j];
    m /= (double)Bn;
    double v = 0.0;
    for (int b = 0; b < Bn; b++) {
        double dd = (double)Xraw[b * F + j] - m;
        v += dd * dd;
    }
    v /= (double)Bn;
    float sc = g[j] * (float)(1.0 / sqrt(v + 1e-5));
    float sh = be[j] - (float)m * sc;
    for (int b = 0; b < Bn; b++) Y[b * F + j] = gelu_f(Xraw[b * F + j] * sc + sh);
}

// ---------------------------------------------------------------------------
extern "C" void kernel_launch(void* const* d_in, const int* in_sizes, int n_in,
                              void* d_out, int out_size, void* d_ws, size_t ws_size,
                              hipStream_t stream) {
    const float* x     = (const float*)d_in[0];
    const float* B_ff  = (const float*)d_in[1];
    const float* mlp_W = (const float*)d_in[2];
    const float* permx = (const float*)d_in[3];
    const float* W1 = (const float*)d_in[4];
    const float* b1 = (const float*)d_in[5];
    const float* S1 = (const float*)d_in[6];
    const float* W2 = (const float*)d_in[7];
    const float* b2 = (const float*)d_in[8];
    const float* S2 = (const float*)d_in[9];
    const float* W3 = (const float*)d_in[10];
    const float* b3 = (const float*)d_in[11];
    const float* S3 = (const float*)d_in[12];
    const float* W4 = (const float*)d_in[13];
    const float* b4 = (const float*)d_in[14];
    const float* S4 = (const float*)d_in[15];
    const float* W5 = (const float*)d_in[16];
    const float* g5 = (const float*)d_in[17];
    const float* be5 = (const float*)d_in[18];
    const float* L1 = (const float*)d_in[19];
    const float* g6 = (const float*)d_in[20];
    const float* be6 = (const float*)d_in[21];
    const float* L2 = (const float*)d_in[22];
    const float* bL2 = (const float*)d_in[23];
    const float* g7 = (const float*)d_in[24];
    const float* be7 = (const float*)d_in[25];
    const float* L3 = (const float*)d_in[26];
    const float* bL3 = (const float*)d_in[27];
    float* outp = (float*)d_out;

    const int BN = BSZ * NPT;  // 16384

    // workspace layout (float units; 16B-aligned). Unions:
    //   f5 aliases Zbig (Zbig dead after L4 GEMM);
    //   partS/partQ alias Pb (Pb dead after L4 agg; 4 MB << Pb's 17.7 MB).
    float* ws = (float*)d_ws;
    float* pts   = ws;                         // 49152
    int*   idxb  = (int*)(ws + 49152);         // 491520 ints
    float* Pb    = ws + 540672;                // 4423680
    float* feat  = Pb + 4423680;               // 8388608 (x1|x2|x3|x4, stride 512)
    float* Zbig  = feat + 8388608;             // 20971520 (max layer: 16384x1280)
    float* f5    = Zbig;                       // union: 16777216
    float* WZ    = Zbig + 20971520;            // 327680 (max 1280x256)
    float* scb   = WZ + 327680;                // 1024
    float* shb   = scb + 1024;                 // 1024
    float* hb    = shb + 1024;                 // 32768
    float* raw1  = hb + 32768;                 // 8192
    float* y1    = raw1 + 8192;                // 8192
    float* raw2  = y1 + 8192;                  // 4096
    float* y2    = raw2 + 4096;                // 4096
    double* partS = (double*)Pb;               // union: 262144 doubles
    double* partQ = partS + 262144;            // 262144 doubles
    size_t need_bytes = (size_t)((y2 + 4096) - ws) * sizeof(float);
    if (ws_size < need_bytes) return;

    transpose_kernel<<<(BN + 255) / 256, 256, 0, stream>>>(x, pts);
    knn_kernel<<<BN, 64, 0, stream>>>(pts, idxb);
    basis_kernel<<<BN, 64, 0, stream>>>(pts, idxb, B_ff, mlp_W, permx, Pb);

    // ---- layer 1: CIN=3, K=27+3=30 pad 32, N=64 ----
    prep_wz<<<(32 * 64 + 255) / 256, 256, 0, stream>>>(W1, S1, WZ, 27, 3, 64, 32);
    agg_kernel<3><<<BN, 256, 0, stream>>>(pts, 3, Pb, idxb, Zbig, 32);
    gemm_f32<64, true, true><<<dim3(1, 128), 256, 0, stream>>>(
        Zbig, 32, WZ, 64, 32, b1, feat + 0, 512);
    // ---- layer 2: CIN=64, K=576+64=640, N=64 ----
    prep_wz<<<(640 * 64 + 255) / 256, 256, 0, stream>>>(W2, S2, WZ, 576, 64, 64, 640);
    agg_kernel<64><<<BN, 256, 0, stream>>>(feat + 0, 512, Pb, idxb, Zbig, 640);
    gemm_f32<64, true, true><<<dim3(1, 128), 256, 0, stream>>>(
        Zbig, 640, WZ, 64, 640, b2, feat + 64, 512);
    // ---- layer 3: CIN=64, K=640, N=128 ----
    prep_wz<<<(640 * 128 + 255) / 256, 256, 0, stream>>>(W3, S3, WZ, 576, 64, 128, 640);
    agg_kernel<64><<<BN, 256, 0, stream>>>(feat + 64, 512, Pb, idxb, Zbig, 640);
    gemm_f32<64, true, true><<<dim3(2, 128), 256, 0, stream>>>(
        Zbig, 640, WZ, 128, 640, b3, feat + 128, 512);
    // ---- layer 4: CIN=128, K=1152+128=1280, N=256 ----
    prep_wz<<<(1280 * 256 + 255) / 256, 256, 0, stream>>>(W4, S4, WZ, 1152, 128, 256, 1280);
    agg_kernel<128><<<BN, 256, 0, stream>>>(feat + 128, 512, Pb, idxb, Zbig, 1280);
    gemm_f32<128, true, true><<<dim3(2, 128), 256, 0, stream>>>(
        Zbig, 1280, WZ, 256, 1280, b4, feat + 256, 512);

    // ---- conv5: f5[BN,1024] = feat[BN,512] @ W5 (Zbig dead -> f5 reuses it) ----
    gemm_f32<128, false, false><<<dim3(8, 128), 256, 0, stream>>>(
        feat, 512, W5, 1024, 512, nullptr, f5, 1024);

    // ---- BN stats (deterministic 2-stage; partials alias dead Pb) ----
    stats_partial<<<256, 256, 0, stream>>>(f5, partS, partQ);
    stats_reduce<<<4, 256, 0, stream>>>(partS, partQ, g5, be5, scb, shb);
    pool_kernel<<<BSZ * 16, 256, 0, stream>>>(f5, scb, shb, hb);

    fc_kernel<<<(BSZ * 512 + 255) / 256, 256, 0, stream>>>(hb, L1, nullptr, raw1, BSZ, 2048, 512);
    bn_gelu_head<<<2, 256, 0, stream>>>(raw1, g6, be6, y1, BSZ, 512);
    fc_kernel<<<(BSZ * 256 + 255) / 256, 256, 0, stream>>>(y1, L2, bL2, raw2, BSZ, 512, 256);
    bn_gelu_head<<<1, 256, 0, stream>>>(raw2, g7, be7, y2, BSZ, 256);
    fc_kernel<<<(BSZ * 40 + 255) / 256, 256, 0, stream>>>(y2, L3, bL3, outp, BSZ, 256, 40);
}

// Round 5
// 1259.874 us; speedup vs baseline: 2.2854x; 1.4788x over previous
//
#include <hip/hip_runtime.h>
#include <hip/hip_bf16.h>
#include <cstddef>

#define BSZ 16
#define NPT 1024
#define KNN 30
#define TKR 9
#define FLT_BIG 3.402823466e+38f
#define DBL_BIG 1.0e300

__device__ __forceinline__ float gelu_f(float x) {
    return 0.5f * x * (1.0f + erff(x * 0.7071067811865476f));
}

// ---------------------------------------------------------------------------
// 1. transpose x [B,3,N] -> pts [B,N,3]
// ---------------------------------------------------------------------------
__global__ __launch_bounds__(256) void transpose_kernel(
    const float* __restrict__ x, float* __restrict__ pts) {
    int t = blockIdx.x * 256 + threadIdx.x;
    if (t >= BSZ * NPT) return;
    int b = t >> 10, n = t & 1023;
    const float* xp = x + (size_t)b * 3 * NPT;
    pts[t * 3 + 0] = xp[n];
    pts[t * 3 + 1] = xp[NPT + n];
    pts[t * 3 + 2] = xp[2 * NPT + n];
}

// ---------------------------------------------------------------------------
// 2. kNN, REGISTER-ONLY: one wave per point. fp64 distances for exact top_k
//    ordering vs the fp64 gold ref. Zero shared state -> deterministic.
// ---------------------------------------------------------------------------
__global__ __launch_bounds__(64) void knn_kernel(
    const float* __restrict__ pts, int* __restrict__ idx) {
    int lane = threadIdx.x & 63;
    int bn_ = blockIdx.x;
    int b = bn_ >> 10;
    double px = (double)pts[(size_t)bn_ * 3 + 0];
    double py = (double)pts[(size_t)bn_ * 3 + 1];
    double pz = (double)pts[(size_t)bn_ * 3 + 2];
    double xn = px * px + py * py + pz * pz;
    const float* pb = pts + (size_t)(b << 10) * 3;
    int base = lane * 16;
    double cand[16];
    #pragma unroll
    for (int j = 0; j < 16; j++) {
        int m = base + j;
        double qx = (double)pb[m * 3 + 0];
        double qy = (double)pb[m * 3 + 1];
        double qz = (double)pb[m * 3 + 2];
        double inner = px * qx + py * qy + pz * qz;
        double xm = qx * qx + qy * qy + qz * qz;
        cand[j] = 2.0 * inner - xn - xm;
    }
    int* op = idx + (size_t)bn_ * KNN;
    for (int it = 0; it < KNN; it++) {
        double bv = -DBL_BIG;
        int bi = 0x7fffffff;
        #pragma unroll
        for (int j = 0; j < 16; j++) {
            if (cand[j] > bv) { bv = cand[j]; bi = base + j; }  // strict > : lowest idx
        }
        #pragma unroll
        for (int s = 1; s < 64; s <<= 1) {
            double ov = __shfl_xor(bv, s, 64);
            int oi = __shfl_xor(bi, s, 64);
            if (ov > bv || (ov == bv && oi < bi)) { bv = ov; bi = oi; }
        }
        if (lane == 0) op[it] = bi;
        #pragma unroll
        for (int j = 0; j < 16; j++) {
            if (base + j == bi) cand[j] = -DBL_BIG;   // register kill, exact
        }
    }
}

// ---------------------------------------------------------------------------
// 3. basis: Fourier feats -> sparsemax(w) -> P[k,t] per point. Block = 64.
// ---------------------------------------------------------------------------
__global__ __launch_bounds__(64) void basis_kernel(
    const float* __restrict__ pts, const int* __restrict__ idx,
    const float* __restrict__ B_ff, const float* __restrict__ mlp_W,
    const float* __restrict__ permx, float* __restrict__ P) {
    __shared__ float npt[KNN * 3];
    __shared__ float feats[7 * KNN];
    __shared__ float sc[64];
    __shared__ float zl[16];
    __shared__ float w[16];
    int bn_ = blockIdx.x;
    int b = bn_ >> 10;
    int tid = threadIdx.x;
    const int* ip = idx + (size_t)bn_ * KNN;
    if (tid < KNN) {
        int m = ip[tid];
        const float* q = pts + ((size_t)(b << 10) + m) * 3;
        npt[tid * 3 + 0] = q[0];
        npt[tid * 3 + 1] = q[1];
        npt[tid * 3 + 2] = q[2];
    }
    __syncthreads();
    if (tid < KNN) {
        float sx = npt[0], sy = npt[1], sz = npt[2];
        float rx = npt[tid * 3 + 0] - sx;
        float ry = npt[tid * 3 + 1] - sy;
        float rz = npt[tid * 3 + 2] - sz;
        float sq = rx * rx + ry * ry + rz * rz;
        float dist = (sq > 0.0f) ? sqrtf(sq) : 0.0f;
        feats[tid * 7 + 0] = sx;
        feats[tid * 7 + 1] = sy;
        feats[tid * 7 + 2] = sz;
        feats[tid * 7 + 3] = rx;
        feats[tid * 7 + 4] = ry;
        feats[tid * 7 + 5] = rz;
        feats[tid * 7 + 6] = dist;
    }
    __syncthreads();
    if (tid < 32) {
        float acc = 0.0f;
        for (int i = 0; i < 7 * KNN; i++) acc += feats[i] * B_ff[i * 32 + tid];
        float ffv = 6.283185307179586f * acc;
        sc[tid] = sinf(ffv);
        sc[tid + 32] = cosf(ffv);
    }
    __syncthreads();
    if (tid < 16) {
        float acc = 0.0f;
        for (int j = 0; j < 64; j++) acc += sc[j] * mlp_W[j * 16 + tid];
        zl[tid] = acc;
    }
    __syncthreads();
    if (tid == 0) {
        float zs[16];
        for (int i = 0; i < 16; i++) zs[i] = zl[i];
        for (int i = 1; i < 16; i++) {          // insertion sort descending
            float key = zs[i]; int j = i - 1;
            while (j >= 0 && zs[j] < key) { zs[j + 1] = zs[j]; j--; }
            zs[j + 1] = key;
        }
        float cs = 0.0f, csarr[16];
        int cnt = 0;
        for (int j = 0; j < 16; j++) {
            cs += zs[j];
            csarr[j] = cs;
            if (1.0f + (float)(j + 1) * zs[j] > cs) cnt++;
        }
        float tau = (csarr[cnt - 1] - 1.0f) / (float)cnt;
        for (int i = 0; i < 16; i++) w[i] = fmaxf(zl[i] - tau, 0.0f);
    }
    __syncthreads();
    float* Pp = P + (size_t)bn_ * (KNN * TKR);
    for (int e = tid; e < KNN * TKR; e += 64) {
        int k = e / TKR, t = e - TKR * k;
        float acc = 0.0f;
        for (int i = 0; i < 16; i++) acc += w[i] * permx[(i * KNN + k) * TKR + t];
        Pp[e] = acc;
    }
}

// ---------------------------------------------------------------------------
// 4a. agg: Z[bn, t*CIN+c] = sum_k nb[k,c]*P[k,t]; Z[bn, 9*CIN+c] = self[c];
//     zero-pad to kpad. One block per point.
// ---------------------------------------------------------------------------
template <int CIN>
__global__ __launch_bounds__(256) void agg_kernel(
    const float* __restrict__ ft, int ftst,
    const float* __restrict__ P, const int* __restrict__ idx,
    float* __restrict__ Z, int kpad) {
    __shared__ float sP[KNN * TKR];
    __shared__ float sNb[KNN * CIN];
    __shared__ int sIdx[KNN];
    int bn_ = blockIdx.x;
    int b = bn_ >> 10;
    int tid = threadIdx.x;
    if (tid < KNN) sIdx[tid] = idx[(size_t)bn_ * KNN + tid];
    for (int e = tid; e < KNN * TKR; e += 256) sP[e] = P[(size_t)bn_ * (KNN * TKR) + e];
    __syncthreads();
    for (int e = tid; e < KNN * CIN; e += 256) {
        int k = e / CIN, c = e - k * CIN;
        sNb[e] = ft[((size_t)(b << 10) + sIdx[k]) * ftst + c];
    }
    __syncthreads();
    float* zp = Z + (size_t)bn_ * kpad;
    const int KW = TKR * CIN;
    for (int e = tid; e < kpad; e += 256) {
        float v;
        if (e < KW) {
            int t = e / CIN, c = e - t * CIN;
            float acc = 0.0f;
            #pragma unroll
            for (int k = 0; k < KNN; k++) acc += sNb[k * CIN + c] * sP[k * TKR + t];
            v = acc;
        } else if (e < KW + CIN) {
            v = ft[(size_t)bn_ * ftst + (e - KW)];
        } else {
            v = 0.0f;
        }
        zp[e] = v;
    }
}

// ---------------------------------------------------------------------------
// 4b. prep WZ = [W ; S ; 0-pad]  (kpad x N)
// ---------------------------------------------------------------------------
__global__ __launch_bounds__(256) void prep_wz(
    const float* __restrict__ W, const float* __restrict__ S,
    float* __restrict__ WZ, int KW, int KS, int N, int kpad) {
    int t = blockIdx.x * 256 + threadIdx.x;
    if (t >= kpad * N) return;
    int k = t / N, n = t - k * N;
    float v = 0.0f;
    if (k < KW) v = W[(size_t)k * N + n];
    else if (k < KW + KS) v = S[(size_t)(k - KW) * N + n];
    WZ[t] = v;
}

// ---------------------------------------------------------------------------
// 5. fp32 tiled GEMM: C[M,N] = act(A[M,K]@B[K,N] + bias). TM=128, 256 thr,
//    micro-tile 8 rows x NC cols split as 4x4 quadrants at +64 offsets.
// ---------------------------------------------------------------------------
template <int TN, bool GELU, bool HASBIAS>
__global__ __launch_bounds__(256) void gemm_f32(
    const float* __restrict__ A, int lda,
    const float* __restrict__ B, int ldb, int K,
    const float* __restrict__ bias,
    float* __restrict__ C, int ldc) {
    __shared__ float As[16][128];
    __shared__ float Bs[16][TN];
    constexpr int NC = TN / 16;            // 8 (TN=128) or 4 (TN=64)
    int tid = threadIdx.x;
    int tx = tid & 15, ty = tid >> 4;
    int m0 = blockIdx.y * 128, n0 = blockIdx.x * TN;
    float acc[8][NC];
    #pragma unroll
    for (int i = 0; i < 8; i++)
        #pragma unroll
        for (int j = 0; j < NC; j++) acc[i][j] = 0.0f;

    int ar = tid >> 1, ac0 = (tid & 1) * 8;
    const float* aptr = A + (size_t)(m0 + ar) * lda + ac0;

    for (int k0 = 0; k0 < K; k0 += 16) {
        float4 a0 = *(const float4*)(aptr + k0);
        float4 a1 = *(const float4*)(aptr + k0 + 4);
        As[ac0 + 0][ar] = a0.x; As[ac0 + 1][ar] = a0.y;
        As[ac0 + 2][ar] = a0.z; As[ac0 + 3][ar] = a0.w;
        As[ac0 + 4][ar] = a1.x; As[ac0 + 5][ar] = a1.y;
        As[ac0 + 6][ar] = a1.z; As[ac0 + 7][ar] = a1.w;
        if (TN == 128) {
            int r = tid >> 5, c = (tid & 31) * 4;
            const float* bp = B + (size_t)(k0 + r) * ldb + n0 + c;
            float4 b0 = *(const float4*)bp;
            float4 b1 = *(const float4*)(bp + (size_t)8 * ldb);
            *(float4*)&Bs[r][c] = b0;
            *(float4*)&Bs[r + 8][c] = b1;
        } else {
            int r = tid >> 4, c = (tid & 15) * 4;
            float4 b0 = *(const float4*)(B + (size_t)(k0 + r) * ldb + n0 + c);
            *(float4*)&Bs[r][c] = b0;
        }
        __syncthreads();
        #pragma unroll
        for (int kk = 0; kk < 16; kk++) {
            float av[8], bv[NC];
            *(float4*)&av[0] = *(const float4*)&As[kk][ty * 4];
            *(float4*)&av[4] = *(const float4*)&As[kk][64 + ty * 4];
            *(float4*)&bv[0] = *(const float4*)&Bs[kk][tx * 4];
            if (TN == 128) *(float4*)&bv[4] = *(const float4*)&Bs[kk][64 + tx * 4];
            #pragma unroll
            for (int i = 0; i < 8; i++)
                #pragma unroll
                for (int j = 0; j < NC; j++) acc[i][j] += av[i] * bv[j];
        }
        __syncthreads();
    }
    #pragma unroll
    for (int hi = 0; hi < 2; hi++) {
        #pragma unroll
        for (int i = 0; i < 4; i++) {
            int r = m0 + hi * 64 + ty * 4 + i;
            #pragma unroll
            for (int hj = 0; hj < NC / 4; hj++) {
                int c = n0 + hj * 64 + tx * 4;
                float v[4];
                #pragma unroll
                for (int j = 0; j < 4; j++) {
                    float t = acc[hi * 4 + i][hj * 4 + j];
                    if (HASBIAS) t += bias[c + j];
                    if (GELU) t = gelu_f(t);
                    v[j] = t;
                }
                *(float4*)(C + (size_t)r * ldc + c) = *(float4*)v;
            }
        }
    }
}

// ---------------------------------------------------------------------------
// 6. BN stats, two-stage deterministic (NO atomics, NO memset).
// ---------------------------------------------------------------------------
__global__ __launch_bounds__(256) void stats_partial(
    const float* __restrict__ f5, double* __restrict__ partS,
    double* __restrict__ partQ) {
    int tid = threadIdx.x;
    double s[4] = {0.0, 0.0, 0.0, 0.0};
    double q[4] = {0.0, 0.0, 0.0, 0.0};
    int p0 = blockIdx.x * 64;
    for (int p = p0; p < p0 + 64; p++) {
        const float* row = f5 + (size_t)p * 1024;
        #pragma unroll
        for (int k = 0; k < 4; k++) {
            double v = (double)row[tid + 256 * k];
            s[k] += v;
            q[k] += v * v;
        }
    }
    #pragma unroll
    for (int k = 0; k < 4; k++) {
        partS[(size_t)blockIdx.x * 1024 + tid + 256 * k] = s[k];
        partQ[(size_t)blockIdx.x * 1024 + tid + 256 * k] = q[k];
    }
}

__global__ __launch_bounds__(256) void stats_reduce(
    const double* __restrict__ partS, const double* __restrict__ partQ,
    const float* __restrict__ g, const float* __restrict__ be,
    float* __restrict__ scaleb, float* __restrict__ shiftb) {
    int e = blockIdx.x * 256 + threadIdx.x;
    if (e >= 1024) return;
    double s = 0.0, q = 0.0;
    for (int b = 0; b < 256; b++) {
        s += partS[(size_t)b * 1024 + e];
        q += partQ[(size_t)b * 1024 + e];
    }
    double m = s * (1.0 / 16384.0);
    double v = q * (1.0 / 16384.0) - m * m;
    float sc = g[e] * (float)(1.0 / sqrt(v + 1e-5));
    scaleb[e] = sc;
    shiftb[e] = be[e] - (float)m * sc;
}

// ---------------------------------------------------------------------------
// 7. pool: h[b, 0:1024] = max_n gelu(bn(f5)); h[b,1024:2048] = mean_n
// ---------------------------------------------------------------------------
__global__ __launch_bounds__(256) void pool_kernel(
    const float* __restrict__ f5, const float* __restrict__ scaleb,
    const float* __restrict__ shiftb, float* __restrict__ h) {
    int b = blockIdx.x >> 4;
    int g = blockIdx.x & 15;
    int e = g * 64 + (threadIdx.x & 63);
    int nlane = threadIdx.x >> 6;
    float sc = scaleb[e], sh = shiftb[e];
    float vmax = -FLT_BIG;
    double vsum = 0.0;
    for (int n = nlane; n < NPT; n += 4) {
        float v = f5[((size_t)b * NPT + n) * 1024 + e];
        v = gelu_f(v * sc + sh);
        vmax = fmaxf(vmax, v);
        vsum += (double)v;
    }
    __shared__ float smax[256];
    __shared__ double ssum[256];
    smax[threadIdx.x] = vmax;
    ssum[threadIdx.x] = vsum;
    __syncthreads();
    if (nlane == 0) {
        for (int i = 1; i < 4; i++) {
            vmax = fmaxf(vmax, smax[threadIdx.x + 64 * i]);
            vsum += ssum[threadIdx.x + 64 * i];
        }
        h[(size_t)b * 2048 + e] = vmax;
        h[(size_t)b * 2048 + 1024 + e] = (float)(vsum * (1.0 / 1024.0));
    }
}

// ---------------------------------------------------------------------------
// 8. FC head, split-K (fp64, deterministic).
//    Stage 1: thread per (chunk,b,j) -> partial over In/KC inputs.
//    Stage 2: thread per (b,j) -> sum KC partials in order + bias.
// ---------------------------------------------------------------------------
__global__ __launch_bounds__(256) void fc_split(
    const float* __restrict__ X, const float* __restrict__ W,
    double* __restrict__ part, int Bn, int In, int Out, int KC) {
    int tid = blockIdx.x * 256 + threadIdx.x;
    if (tid >= Bn * Out * KC) return;
    int chunk = tid / (Bn * Out);
    int r = tid - chunk * (Bn * Out);
    int b = r / Out, j = r - b * Out;
    int len = In / KC;
    int i0 = chunk * len;
    const float* x = X + (size_t)b * In + i0;
    const float* w = W + (size_t)i0 * Out + j;
    double acc = 0.0;
    for (int i = 0; i < len; i++) acc += (double)x[i] * (double)w[(size_t)i * Out];
    part[tid] = acc;
}

__global__ __launch_bounds__(256) void fc_reduce(
    const double* __restrict__ part, const float* __restrict__ bias,
    float* __restrict__ Y, int Bn, int Out, int KC) {
    int r = blockIdx.x * 256 + threadIdx.x;
    if (r >= Bn * Out) return;
    int j = r % Out;
    double acc = bias ? (double)bias[j] : 0.0;
    for (int c = 0; c < KC; c++) acc += part[(size_t)c * (Bn * Out) + r];
    Y[r] = (float)acc;
}

__global__ __launch_bounds__(256) void bn_gelu_head(
    const float* __restrict__ Xraw, const float* __restrict__ g,
    const float* __restrict__ be, float* __restrict__ Y, int Bn, int F) {
    int j = blockIdx.x * 256 + threadIdx.x;
    if (j >= F) return;
    double m = 0.0;
    for (int b = 0; b < Bn; b++) m += (double)Xraw[b * F + j];
    m /= (double)Bn;
    double v = 0.0;
    for (int b = 0; b < Bn; b++) {
        double dd = (double)Xraw[b * F + j] - m;
        v += dd * dd;
    }
    v /= (double)Bn;
    float sc = g[j] * (float)(1.0 / sqrt(v + 1e-5));
    float sh = be[j] - (float)m * sc;
    for (int b = 0; b < Bn; b++) Y[b * F + j] = gelu_f(Xraw[b * F + j] * sc + sh);
}

// ---------------------------------------------------------------------------
extern "C" void kernel_launch(void* const* d_in, const int* in_sizes, int n_in,
                              void* d_out, int out_size, void* d_ws, size_t ws_size,
                              hipStream_t stream) {
    const float* x     = (const float*)d_in[0];
    const float* B_ff  = (const float*)d_in[1];
    const float* mlp_W = (const float*)d_in[2];
    const float* permx = (const float*)d_in[3];
    const float* W1 = (const float*)d_in[4];
    const float* b1 = (const float*)d_in[5];
    const float* S1 = (const float*)d_in[6];
    const float* W2 = (const float*)d_in[7];
    const float* b2 = (const float*)d_in[8];
    const float* S2 = (const float*)d_in[9];
    const float* W3 = (const float*)d_in[10];
    const float* b3 = (const float*)d_in[11];
    const float* S3 = (const float*)d_in[12];
    const float* W4 = (const float*)d_in[13];
    const float* b4 = (const float*)d_in[14];
    const float* S4 = (const float*)d_in[15];
    const float* W5 = (const float*)d_in[16];
    const float* g5 = (const float*)d_in[17];
    const float* be5 = (const float*)d_in[18];
    const float* L1 = (const float*)d_in[19];
    const float* g6 = (const float*)d_in[20];
    const float* be6 = (const float*)d_in[21];
    const float* L2 = (const float*)d_in[22];
    const float* bL2 = (const float*)d_in[23];
    const float* g7 = (const float*)d_in[24];
    const float* be7 = (const float*)d_in[25];
    const float* L3 = (const float*)d_in[26];
    const float* bL3 = (const float*)d_in[27];
    float* outp = (float*)d_out;

    const int BN = BSZ * NPT;  // 16384

    // workspace layout (float units; 16B-aligned). Unions:
    //   f5 aliases Zbig (Zbig dead after L4 GEMM);
    //   partS/partQ/partF alias Pb (Pb dead after L4 agg; 5 MB << 17.7 MB).
    float* ws = (float*)d_ws;
    float* pts   = ws;                         // 49152
    int*   idxb  = (int*)(ws + 49152);         // 491520 ints
    float* Pb    = ws + 540672;                // 4423680
    float* feat  = Pb + 4423680;               // 8388608 (x1|x2|x3|x4, stride 512)
    float* Zbig  = feat + 8388608;             // 20971520 (max layer: 16384x1280)
    float* f5    = Zbig;                       // union: 16777216
    float* WZ    = Zbig + 20971520;            // 327680 (max 1280x256)
    float* scb   = WZ + 327680;                // 1024
    float* shb   = scb + 1024;                 // 1024
    float* hb    = shb + 1024;                 // 32768
    float* raw1  = hb + 32768;                 // 8192
    float* y1    = raw1 + 8192;                // 8192
    float* raw2  = y1 + 8192;                  // 4096
    float* y2    = raw2 + 4096;                // 4096
    double* partS = (double*)Pb;               // union: 262144 doubles
    double* partQ = partS + 262144;            // 262144 doubles
    double* partF = partQ + 262144;            // 131072 doubles (max FC partials)
    size_t need_bytes = (size_t)((y2 + 4096) - ws) * sizeof(float);
    if (ws_size < need_bytes) return;

    transpose_kernel<<<(BN + 255) / 256, 256, 0, stream>>>(x, pts);
    knn_kernel<<<BN, 64, 0, stream>>>(pts, idxb);
    basis_kernel<<<BN, 64, 0, stream>>>(pts, idxb, B_ff, mlp_W, permx, Pb);

    // ---- layer 1: CIN=3, K=27+3=30 pad 32, N=64 ----
    prep_wz<<<(32 * 64 + 255) / 256, 256, 0, stream>>>(W1, S1, WZ, 27, 3, 64, 32);
    agg_kernel<3><<<BN, 256, 0, stream>>>(pts, 3, Pb, idxb, Zbig, 32);
    gemm_f32<64, true, true><<<dim3(1, 128), 256, 0, stream>>>(
        Zbig, 32, WZ, 64, 32, b1, feat + 0, 512);
    // ---- layer 2: CIN=64, K=576+64=640, N=64 ----
    prep_wz<<<(640 * 64 + 255) / 256, 256, 0, stream>>>(W2, S2, WZ, 576, 64, 64, 640);
    agg_kernel<64><<<BN, 256, 0, stream>>>(feat + 0, 512, Pb, idxb, Zbig, 640);
    gemm_f32<64, true, true><<<dim3(1, 128), 256, 0, stream>>>(
        Zbig, 640, WZ, 64, 640, b2, feat + 64, 512);
    // ---- layer 3: CIN=64, K=640, N=128 ----
    prep_wz<<<(640 * 128 + 255) / 256, 256, 0, stream>>>(W3, S3, WZ, 576, 64, 128, 640);
    agg_kernel<64><<<BN, 256, 0, stream>>>(feat + 64, 512, Pb, idxb, Zbig, 640);
    gemm_f32<64, true, true><<<dim3(2, 128), 256, 0, stream>>>(
        Zbig, 640, WZ, 128, 640, b3, feat + 128, 512);
    // ---- layer 4: CIN=128, K=1152+128=1280, N=256 ----
    prep_wz<<<(1280 * 256 + 255) / 256, 256, 0, stream>>>(W4, S4, WZ, 1152, 128, 256, 1280);
    agg_kernel<128><<<BN, 256, 0, stream>>>(feat + 128, 512, Pb, idxb, Zbig, 1280);
    gemm_f32<128, true, true><<<dim3(2, 128), 256, 0, stream>>>(
        Zbig, 1280, WZ, 256, 1280, b4, feat + 256, 512);

    // ---- conv5: f5[BN,1024] = feat[BN,512] @ W5 (Zbig dead -> f5 reuses it) ----
    gemm_f32<128, false, false><<<dim3(8, 128), 256, 0, stream>>>(
        feat, 512, W5, 1024, 512, nullptr, f5, 1024);

    // ---- BN stats (deterministic 2-stage; partials alias dead Pb) ----
    stats_partial<<<256, 256, 0, stream>>>(f5, partS, partQ);
    stats_reduce<<<4, 256, 0, stream>>>(partS, partQ, g5, be5, scb, shb);
    pool_kernel<<<BSZ * 16, 256, 0, stream>>>(f5, scb, shb, hb);

    // ---- FC head, split-K fp64 ----
    // L1: 2048 -> 512, KC=16
    fc_split<<<(BSZ * 512 * 16 + 255) / 256, 256, 0, stream>>>(hb, L1, partF, BSZ, 2048, 512, 16);
    fc_reduce<<<(BSZ * 512 + 255) / 256, 256, 0, stream>>>(partF, nullptr, raw1, BSZ, 512, 16);
    bn_gelu_head<<<2, 256, 0, stream>>>(raw1, g6, be6, y1, BSZ, 512);
    // L2: 512 -> 256, KC=8
    fc_split<<<(BSZ * 256 * 8 + 255) / 256, 256, 0, stream>>>(y1, L2, partF, BSZ, 512, 256, 8);
    fc_reduce<<<(BSZ * 256 + 255) / 256, 256, 0, stream>>>(partF, bL2, raw2, BSZ, 256, 8);
    bn_gelu_head<<<1, 256, 0, stream>>>(raw2, g7, be7, y2, BSZ, 256);
    // L3: 256 -> 40, KC=4
    fc_split<<<(BSZ * 40 * 4 + 255) / 256, 256, 0, stream>>>(y2, L3, partF, BSZ, 256, 40, 4);
    fc_reduce<<<(BSZ * 40 + 255) / 256, 256, 0, stream>>>(partF, bL3, outp, BSZ, 40, 4);
}

// Round 6
// 1257.097 us; speedup vs baseline: 2.2904x; 1.0022x over previous
//
#include <hip/hip_runtime.h>
#include <hip/hip_bf16.h>
#include <cstddef>

#define BSZ 16
#define NPT 1024
#define KNN 30
#define TKR 9
#define FLT_BIG 3.402823466e+38f
#define DBL_BIG 1.0e300

__device__ __forceinline__ float gelu_f(float x) {
    return 0.5f * x * (1.0f + erff(x * 0.7071067811865476f));
}

// ---------------------------------------------------------------------------
// 1. transpose x [B,3,N] -> pts [B,N,3]
// ---------------------------------------------------------------------------
__global__ __launch_bounds__(256) void transpose_kernel(
    const float* __restrict__ x, float* __restrict__ pts) {
    int t = blockIdx.x * 256 + threadIdx.x;
    if (t >= BSZ * NPT) return;
    int b = t >> 10, n = t & 1023;
    const float* xp = x + (size_t)b * 3 * NPT;
    pts[t * 3 + 0] = xp[n];
    pts[t * 3 + 1] = xp[NPT + n];
    pts[t * 3 + 2] = xp[2 * NPT + n];
}

// ---------------------------------------------------------------------------
// 2. kNN, REGISTER-ONLY: one wave per point. fp64 distances for exact top_k
//    ordering vs the fp64 gold ref. Zero shared state -> deterministic.
// ---------------------------------------------------------------------------
__global__ __launch_bounds__(64) void knn_kernel(
    const float* __restrict__ pts, int* __restrict__ idx) {
    int lane = threadIdx.x & 63;
    int bn_ = blockIdx.x;
    int b = bn_ >> 10;
    double px = (double)pts[(size_t)bn_ * 3 + 0];
    double py = (double)pts[(size_t)bn_ * 3 + 1];
    double pz = (double)pts[(size_t)bn_ * 3 + 2];
    double xn = px * px + py * py + pz * pz;
    const float* pb = pts + (size_t)(b << 10) * 3;
    int base = lane * 16;
    double cand[16];
    #pragma unroll
    for (int j = 0; j < 16; j++) {
        int m = base + j;
        double qx = (double)pb[m * 3 + 0];
        double qy = (double)pb[m * 3 + 1];
        double qz = (double)pb[m * 3 + 2];
        double inner = px * qx + py * qy + pz * qz;
        double xm = qx * qx + qy * qy + qz * qz;
        cand[j] = 2.0 * inner - xn - xm;
    }
    int* op = idx + (size_t)bn_ * KNN;
    for (int it = 0; it < KNN; it++) {
        double bv = -DBL_BIG;
        int bi = 0x7fffffff;
        #pragma unroll
        for (int j = 0; j < 16; j++) {
            if (cand[j] > bv) { bv = cand[j]; bi = base + j; }  // strict > : lowest idx
        }
        #pragma unroll
        for (int s = 1; s < 64; s <<= 1) {
            double ov = __shfl_xor(bv, s, 64);
            int oi = __shfl_xor(bi, s, 64);
            if (ov > bv || (ov == bv && oi < bi)) { bv = ov; bi = oi; }
        }
        if (lane == 0) op[it] = bi;
        #pragma unroll
        for (int j = 0; j < 16; j++) {
            if (base + j == bi) cand[j] = -DBL_BIG;   // register kill, exact
        }
    }
}

// ---------------------------------------------------------------------------
// 3. basis: Fourier feats -> sparsemax(w) -> P[k,t] per point. Block = 64.
// ---------------------------------------------------------------------------
__global__ __launch_bounds__(64) void basis_kernel(
    const float* __restrict__ pts, const int* __restrict__ idx,
    const float* __restrict__ B_ff, const float* __restrict__ mlp_W,
    const float* __restrict__ permx, float* __restrict__ P) {
    __shared__ float npt[KNN * 3];
    __shared__ float feats[7 * KNN];
    __shared__ float sc[64];
    __shared__ float zl[16];
    __shared__ float w[16];
    int bn_ = blockIdx.x;
    int b = bn_ >> 10;
    int tid = threadIdx.x;
    const int* ip = idx + (size_t)bn_ * KNN;
    if (tid < KNN) {
        int m = ip[tid];
        const float* q = pts + ((size_t)(b << 10) + m) * 3;
        npt[tid * 3 + 0] = q[0];
        npt[tid * 3 + 1] = q[1];
        npt[tid * 3 + 2] = q[2];
    }
    __syncthreads();
    if (tid < KNN) {
        float sx = npt[0], sy = npt[1], sz = npt[2];
        float rx = npt[tid * 3 + 0] - sx;
        float ry = npt[tid * 3 + 1] - sy;
        float rz = npt[tid * 3 + 2] - sz;
        float sq = rx * rx + ry * ry + rz * rz;
        float dist = (sq > 0.0f) ? sqrtf(sq) : 0.0f;
        feats[tid * 7 + 0] = sx;
        feats[tid * 7 + 1] = sy;
        feats[tid * 7 + 2] = sz;
        feats[tid * 7 + 3] = rx;
        feats[tid * 7 + 4] = ry;
        feats[tid * 7 + 5] = rz;
        feats[tid * 7 + 6] = dist;
    }
    __syncthreads();
    if (tid < 32) {
        float acc = 0.0f;
        for (int i = 0; i < 7 * KNN; i++) acc += feats[i] * B_ff[i * 32 + tid];
        float ffv = 6.283185307179586f * acc;
        sc[tid] = sinf(ffv);
        sc[tid + 32] = cosf(ffv);
    }
    __syncthreads();
    if (tid < 16) {
        float acc = 0.0f;
        for (int j = 0; j < 64; j++) acc += sc[j] * mlp_W[j * 16 + tid];
        zl[tid] = acc;
    }
    __syncthreads();
    if (tid == 0) {
        float zs[16];
        for (int i = 0; i < 16; i++) zs[i] = zl[i];
        for (int i = 1; i < 16; i++) {          // insertion sort descending
            float key = zs[i]; int j = i - 1;
            while (j >= 0 && zs[j] < key) { zs[j + 1] = zs[j]; j--; }
            zs[j + 1] = key;
        }
        float cs = 0.0f, csarr[16];
        int cnt = 0;
        for (int j = 0; j < 16; j++) {
            cs += zs[j];
            csarr[j] = cs;
            if (1.0f + (float)(j + 1) * zs[j] > cs) cnt++;
        }
        float tau = (csarr[cnt - 1] - 1.0f) / (float)cnt;
        for (int i = 0; i < 16; i++) w[i] = fmaxf(zl[i] - tau, 0.0f);
    }
    __syncthreads();
    float* Pp = P + (size_t)bn_ * (KNN * TKR);
    for (int e = tid; e < KNN * TKR; e += 64) {
        int k = e / TKR, t = e - TKR * k;
        float acc = 0.0f;
        for (int i = 0; i < 16; i++) acc += w[i] * permx[(i * KNN + k) * TKR + t];
        Pp[e] = acc;
    }
}

// ---------------------------------------------------------------------------
// 4a. agg: Z[bn, t*CIN+c] = sum_k nb[k,c]*P[k,t]; Z[bn, 9*CIN+c] = self[c];
//     zero-pad to kpad. One block per point.
// ---------------------------------------------------------------------------
template <int CIN>
__global__ __launch_bounds__(256) void agg_kernel(
    const float* __restrict__ ft, int ftst,
    const float* __restrict__ P, const int* __restrict__ idx,
    float* __restrict__ Z, int kpad) {
    __shared__ float sP[KNN * TKR];
    __shared__ float sNb[KNN * CIN];
    __shared__ int sIdx[KNN];
    int bn_ = blockIdx.x;
    int b = bn_ >> 10;
    int tid = threadIdx.x;
    if (tid < KNN) sIdx[tid] = idx[(size_t)bn_ * KNN + tid];
    for (int e = tid; e < KNN * TKR; e += 256) sP[e] = P[(size_t)bn_ * (KNN * TKR) + e];
    __syncthreads();
    for (int e = tid; e < KNN * CIN; e += 256) {
        int k = e / CIN, c = e - k * CIN;
        sNb[e] = ft[((size_t)(b << 10) + sIdx[k]) * ftst + c];
    }
    __syncthreads();
    float* zp = Z + (size_t)bn_ * kpad;
    const int KW = TKR * CIN;
    for (int e = tid; e < kpad; e += 256) {
        float v;
        if (e < KW) {
            int t = e / CIN, c = e - t * CIN;
            float acc = 0.0f;
            #pragma unroll
            for (int k = 0; k < KNN; k++) acc += sNb[k * CIN + c] * sP[k * TKR + t];
            v = acc;
        } else if (e < KW + CIN) {
            v = ft[(size_t)bn_ * ftst + (e - KW)];
        } else {
            v = 0.0f;
        }
        zp[e] = v;
    }
}

// ---------------------------------------------------------------------------
// 4b. prep WZ = [W ; S ; 0-pad]  (kpad x N)
// ---------------------------------------------------------------------------
__global__ __launch_bounds__(256) void prep_wz(
    const float* __restrict__ W, const float* __restrict__ S,
    float* __restrict__ WZ, int KW, int KS, int N, int kpad) {
    int t = blockIdx.x * 256 + threadIdx.x;
    if (t >= kpad * N) return;
    int k = t / N, n = t - k * N;
    float v = 0.0f;
    if (k < KW) v = W[(size_t)k * N + n];
    else if (k < KW + KS) v = S[(size_t)(k - KW) * N + n];
    WZ[t] = v;
}

// ---------------------------------------------------------------------------
// 5. fp32 tiled GEMM, register double-buffered: C = act(A@B + bias).
//    TM in {64,128}, TN in {64,128}, 256 threads. Per-iter: store prefetched
//    regs->LDS, sync, issue next tile's global loads, compute 16-kk from LDS.
//    Accumulation order identical to the non-pipelined version (bit-exact).
// ---------------------------------------------------------------------------
template <int TM, int TN, bool GELU, bool HASBIAS>
__global__ __launch_bounds__(256) void gemm_f32(
    const float* __restrict__ A, int lda,
    const float* __restrict__ B, int ldb, int K,
    const float* __restrict__ bias,
    float* __restrict__ C, int ldc) {
    __shared__ float As[16][TM];
    __shared__ float Bs[16][TN];
    constexpr int RM = TM / 16;            // 8 or 4 rows per thread
    constexpr int NC = TN / 16;            // 8 or 4 cols per thread
    int tid = threadIdx.x;
    int tx = tid & 15, ty = tid >> 4;
    int m0 = blockIdx.y * TM, n0 = blockIdx.x * TN;
    float acc[RM][NC];
    #pragma unroll
    for (int i = 0; i < RM; i++)
        #pragma unroll
        for (int j = 0; j < NC; j++) acc[i][j] = 0.0f;

    int ar, ac0;
    if (TM == 128) { ar = tid >> 1; ac0 = (tid & 1) * 8; }
    else           { ar = tid >> 2; ac0 = (tid & 3) * 4; }
    const float* aptr = A + (size_t)(m0 + ar) * lda + ac0;
    int br, bc;
    if (TN == 128) { br = tid >> 5; bc = (tid & 31) * 4; }
    else           { br = tid >> 4; bc = (tid & 15) * 4; }
    const float* bptr = B + (size_t)br * ldb + n0 + bc;

    float4 pa0, pa1, pb0, pb1;
    pa0 = *(const float4*)(aptr);
    if (TM == 128) pa1 = *(const float4*)(aptr + 4);
    pb0 = *(const float4*)(bptr);
    if (TN == 128) pb1 = *(const float4*)(bptr + (size_t)8 * ldb);

    for (int k0 = 0; k0 < K; k0 += 16) {
        As[ac0 + 0][ar] = pa0.x; As[ac0 + 1][ar] = pa0.y;
        As[ac0 + 2][ar] = pa0.z; As[ac0 + 3][ar] = pa0.w;
        if (TM == 128) {
            As[ac0 + 4][ar] = pa1.x; As[ac0 + 5][ar] = pa1.y;
            As[ac0 + 6][ar] = pa1.z; As[ac0 + 7][ar] = pa1.w;
        }
        *(float4*)&Bs[br][bc] = pb0;
        if (TN == 128) *(float4*)&Bs[br + 8][bc] = pb1;
        __syncthreads();
        if (k0 + 16 < K) {   // prefetch next tile (in flight during compute)
            pa0 = *(const float4*)(aptr + k0 + 16);
            if (TM == 128) pa1 = *(const float4*)(aptr + k0 + 20);
            pb0 = *(const float4*)(bptr + (size_t)(k0 + 16) * ldb);
            if (TN == 128) pb1 = *(const float4*)(bptr + (size_t)(k0 + 24) * ldb);
        }
        #pragma unroll
        for (int kk = 0; kk < 16; kk++) {
            float av[RM], bv[NC];
            *(float4*)&av[0] = *(const float4*)&As[kk][ty * 4];
            if (TM == 128) *(float4*)&av[4] = *(const float4*)&As[kk][64 + ty * 4];
            *(float4*)&bv[0] = *(const float4*)&Bs[kk][tx * 4];
            if (TN == 128) *(float4*)&bv[4] = *(const float4*)&Bs[kk][64 + tx * 4];
            #pragma unroll
            for (int i = 0; i < RM; i++)
                #pragma unroll
                for (int j = 0; j < NC; j++) acc[i][j] += av[i] * bv[j];
        }
        __syncthreads();
    }
    #pragma unroll
    for (int hi = 0; hi < TM / 64; hi++) {
        #pragma unroll
        for (int i = 0; i < 4; i++) {
            int r = m0 + hi * 64 + ty * 4 + i;
            #pragma unroll
            for (int hj = 0; hj < TN / 64; hj++) {
                int c = n0 + hj * 64 + tx * 4;
                float v[4];
                #pragma unroll
                for (int j = 0; j < 4; j++) {
                    float t = acc[hi * 4 + i][hj * 4 + j];
                    if (HASBIAS) t += bias[c + j];
                    if (GELU) t = gelu_f(t);
                    v[j] = t;
                }
                *(float4*)(C + (size_t)r * ldc + c) = *(float4*)v;
            }
        }
    }
}

// ---------------------------------------------------------------------------
// 6. BN stats, two-stage deterministic (NO atomics, NO memset).
// ---------------------------------------------------------------------------
__global__ __launch_bounds__(256) void stats_partial(
    const float* __restrict__ f5, double* __restrict__ partS,
    double* __restrict__ partQ) {
    int tid = threadIdx.x;
    double s[4] = {0.0, 0.0, 0.0, 0.0};
    double q[4] = {0.0, 0.0, 0.0, 0.0};
    int p0 = blockIdx.x * 64;
    for (int p = p0; p < p0 + 64; p++) {
        const float* row = f5 + (size_t)p * 1024;
        #pragma unroll
        for (int k = 0; k < 4; k++) {
            double v = (double)row[tid + 256 * k];
            s[k] += v;
            q[k] += v * v;
        }
    }
    #pragma unroll
    for (int k = 0; k < 4; k++) {
        partS[(size_t)blockIdx.x * 1024 + tid + 256 * k] = s[k];
        partQ[(size_t)blockIdx.x * 1024 + tid + 256 * k] = q[k];
    }
}

__global__ __launch_bounds__(256) void stats_reduce(
    const double* __restrict__ partS, const double* __restrict__ partQ,
    const float* __restrict__ g, const float* __restrict__ be,
    float* __restrict__ scaleb, float* __restrict__ shiftb) {
    int e = blockIdx.x * 256 + threadIdx.x;
    if (e >= 1024) return;
    double s = 0.0, q = 0.0;
    for (int b = 0; b < 256; b++) {
        s += partS[(size_t)b * 1024 + e];
        q += partQ[(size_t)b * 1024 + e];
    }
    double m = s * (1.0 / 16384.0);
    double v = q * (1.0 / 16384.0) - m * m;
    float sc = g[e] * (float)(1.0 / sqrt(v + 1e-5));
    scaleb[e] = sc;
    shiftb[e] = be[e] - (float)m * sc;
}

// ---------------------------------------------------------------------------
// 7. pool: h[b, 0:1024] = max_n gelu(bn(f5)); h[b,1024:2048] = mean_n
// ---------------------------------------------------------------------------
__global__ __launch_bounds__(256) void pool_kernel(
    const float* __restrict__ f5, const float* __restrict__ scaleb,
    const float* __restrict__ shiftb, float* __restrict__ h) {
    int b = blockIdx.x >> 4;
    int g = blockIdx.x & 15;
    int e = g * 64 + (threadIdx.x & 63);
    int nlane = threadIdx.x >> 6;
    float sc = scaleb[e], sh = shiftb[e];
    float vmax = -FLT_BIG;
    double vsum = 0.0;
    for (int n = nlane; n < NPT; n += 4) {
        float v = f5[((size_t)b * NPT + n) * 1024 + e];
        v = gelu_f(v * sc + sh);
        vmax = fmaxf(vmax, v);
        vsum += (double)v;
    }
    __shared__ float smax[256];
    __shared__ double ssum[256];
    smax[threadIdx.x] = vmax;
    ssum[threadIdx.x] = vsum;
    __syncthreads();
    if (nlane == 0) {
        for (int i = 1; i < 4; i++) {
            vmax = fmaxf(vmax, smax[threadIdx.x + 64 * i]);
            vsum += ssum[threadIdx.x + 64 * i];
        }
        h[(size_t)b * 2048 + e] = vmax;
        h[(size_t)b * 2048 + 1024 + e] = (float)(vsum * (1.0 / 1024.0));
    }
}

// ---------------------------------------------------------------------------
// 8. FC head, split-K (fp64, deterministic).
// ---------------------------------------------------------------------------
__global__ __launch_bounds__(256) void fc_split(
    const float* __restrict__ X, const float* __restrict__ W,
    double* __restrict__ part, int Bn, int In, int Out, int KC) {
    int tid = blockIdx.x * 256 + threadIdx.x;
    if (tid >= Bn * Out * KC) return;
    int chunk = tid / (Bn * Out);
    int r = tid - chunk * (Bn * Out);
    int b = r / Out, j = r - b * Out;
    int len = In / KC;
    int i0 = chunk * len;
    const float* x = X + (size_t)b * In + i0;
    const float* w = W + (size_t)i0 * Out + j;
    double acc = 0.0;
    for (int i = 0; i < len; i++) acc += (double)x[i] * (double)w[(size_t)i * Out];
    part[tid] = acc;
}

__global__ __launch_bounds__(256) void fc_reduce(
    const double* __restrict__ part, const float* __restrict__ bias,
    float* __restrict__ Y, int Bn, int Out, int KC) {
    int r = blockIdx.x * 256 + threadIdx.x;
    if (r >= Bn * Out) return;
    int j = r % Out;
    double acc = bias ? (double)bias[j] : 0.0;
    for (int c = 0; c < KC; c++) acc += part[(size_t)c * (Bn * Out) + r];
    Y[r] = (float)acc;
}

__global__ __launch_bounds__(256) void bn_gelu_head(
    const float* __restrict__ Xraw, const float* __restrict__ g,
    const float* __restrict__ be, float* __restrict__ Y, int Bn, int F) {
    int j = blockIdx.x * 256 + threadIdx.x;
    if (j >= F) return;
    double m = 0.0;
    for (int b = 0; b < Bn; b++) m += (double)Xraw[b * F + j];
    m /= (double)Bn;
    double v = 0.0;
    for (int b = 0; b < Bn; b++) {
        double dd = (double)Xraw[b * F + j] - m;
        v += dd * dd;
    }
    v /= (double)Bn;
    float sc = g[j] * (float)(1.0 / sqrt(v + 1e-5));
    float sh = be[j] - (float)m * sc;
    for (int b = 0; b < Bn; b++) Y[b * F + j] = gelu_f(Xraw[b * F + j] * sc + sh);
}

// ---------------------------------------------------------------------------
extern "C" void kernel_launch(void* const* d_in, const int* in_sizes, int n_in,
                              void* d_out, int out_size, void* d_ws, size_t ws_size,
                              hipStream_t stream) {
    const float* x     = (const float*)d_in[0];
    const float* B_ff  = (const float*)d_in[1];
    const float* mlp_W = (const float*)d_in[2];
    const float* permx = (const float*)d_in[3];
    const float* W1 = (const float*)d_in[4];
    const float* b1 = (const float*)d_in[5];
    const float* S1 = (const float*)d_in[6];
    const float* W2 = (const float*)d_in[7];
    const float* b2 = (const float*)d_in[8];
    const float* S2 = (const float*)d_in[9];
    const float* W3 = (const float*)d_in[10];
    const float* b3 = (const float*)d_in[11];
    const float* S3 = (const float*)d_in[12];
    const float* W4 = (const float*)d_in[13];
    const float* b4 = (const float*)d_in[14];
    const float* S4 = (const float*)d_in[15];
    const float* W5 = (const float*)d_in[16];
    const float* g5 = (const float*)d_in[17];
    const float* be5 = (const float*)d_in[18];
    const float* L1 = (const float*)d_in[19];
    const float* g6 = (const float*)d_in[20];
    const float* be6 = (const float*)d_in[21];
    const float* L2 = (const float*)d_in[22];
    const float* bL2 = (const float*)d_in[23];
    const float* g7 = (const float*)d_in[24];
    const float* be7 = (const float*)d_in[25];
    const float* L3 = (const float*)d_in[26];
    const float* bL3 = (const float*)d_in[27];
    float* outp = (float*)d_out;

    const int BN = BSZ * NPT;  // 16384

    // workspace layout (float units; 16B-aligned). Unions:
    //   f5 aliases Zbig (Zbig dead after L4 GEMM);
    //   partS/partQ/partF alias Pb (Pb dead after L4 agg; 5 MB << 17.7 MB).
    float* ws = (float*)d_ws;
    float* pts   = ws;                         // 49152
    int*   idxb  = (int*)(ws + 49152);         // 491520 ints
    float* Pb    = ws + 540672;                // 4423680
    float* feat  = Pb + 4423680;               // 8388608 (x1|x2|x3|x4, stride 512)
    float* Zbig  = feat + 8388608;             // 20971520 (max layer: 16384x1280)
    float* f5    = Zbig;                       // union: 16777216
    float* WZ    = Zbig + 20971520;            // 327680 (max 1280x256)
    float* scb   = WZ + 327680;                // 1024
    float* shb   = scb + 1024;                 // 1024
    float* hb    = shb + 1024;                 // 32768
    float* raw1  = hb + 32768;                 // 8192
    float* y1    = raw1 + 8192;                // 8192
    float* raw2  = y1 + 8192;                  // 4096
    float* y2    = raw2 + 4096;                // 4096
    double* partS = (double*)Pb;               // union: 262144 doubles
    double* partQ = partS + 262144;            // 262144 doubles
    double* partF = partQ + 262144;            // 131072 doubles (max FC partials)
    size_t need_bytes = (size_t)((y2 + 4096) - ws) * sizeof(float);
    if (ws_size < need_bytes) return;

    transpose_kernel<<<(BN + 255) / 256, 256, 0, stream>>>(x, pts);
    knn_kernel<<<BN, 64, 0, stream>>>(pts, idxb);
    basis_kernel<<<BN, 64, 0, stream>>>(pts, idxb, B_ff, mlp_W, permx, Pb);

    // ---- layer 1: CIN=3, K=27+3=30 pad 32, N=64 ----
    prep_wz<<<(32 * 64 + 255) / 256, 256, 0, stream>>>(W1, S1, WZ, 27, 3, 64, 32);
    agg_kernel<3><<<BN, 256, 0, stream>>>(pts, 3, Pb, idxb, Zbig, 32);
    gemm_f32<64, 64, true, true><<<dim3(1, 256), 256, 0, stream>>>(
        Zbig, 32, WZ, 64, 32, b1, feat + 0, 512);
    // ---- layer 2: CIN=64, K=576+64=640, N=64 ----
    prep_wz<<<(640 * 64 + 255) / 256, 256, 0, stream>>>(W2, S2, WZ, 576, 64, 64, 640);
    agg_kernel<64><<<BN, 256, 0, stream>>>(feat + 0, 512, Pb, idxb, Zbig, 640);
    gemm_f32<64, 64, true, true><<<dim3(1, 256), 256, 0, stream>>>(
        Zbig, 640, WZ, 64, 640, b2, feat + 64, 512);
    // ---- layer 3: CIN=64, K=640, N=128 ----
    prep_wz<<<(640 * 128 + 255) / 256, 256, 0, stream>>>(W3, S3, WZ, 576, 64, 128, 640);
    agg_kernel<64><<<BN, 256, 0, stream>>>(feat + 64, 512, Pb, idxb, Zbig, 640);
    gemm_f32<64, 64, true, true><<<dim3(2, 256), 256, 0, stream>>>(
        Zbig, 640, WZ, 128, 640, b3, feat + 128, 512);
    // ---- layer 4: CIN=128, K=1152+128=1280, N=256 ----
    prep_wz<<<(1280 * 256 + 255) / 256, 256, 0, stream>>>(W4, S4, WZ, 1152, 128, 256, 1280);
    agg_kernel<128><<<BN, 256, 0, stream>>>(feat + 128, 512, Pb, idxb, Zbig, 1280);
    gemm_f32<64, 64, true, true><<<dim3(4, 256), 256, 0, stream>>>(
        Zbig, 1280, WZ, 256, 1280, b4, feat + 256, 512);

    // ---- conv5: f5[BN,1024] = feat[BN,512] @ W5 (Zbig dead -> f5 reuses it) ----
    gemm_f32<128, 128, false, false><<<dim3(8, 128), 256, 0, stream>>>(
        feat, 512, W5, 1024, 512, nullptr, f5, 1024);

    // ---- BN stats (deterministic 2-stage; partials alias dead Pb) ----
    stats_partial<<<256, 256, 0, stream>>>(f5, partS, partQ);
    stats_reduce<<<4, 256, 0, stream>>>(partS, partQ, g5, be5, scb, shb);
    pool_kernel<<<BSZ * 16, 256, 0, stream>>>(f5, scb, shb, hb);

    // ---- FC head, split-K fp64 ----
    fc_split<<<(BSZ * 512 * 16 + 255) / 256, 256, 0, stream>>>(hb, L1, partF, BSZ, 2048, 512, 16);
    fc_reduce<<<(BSZ * 512 + 255) / 256, 256, 0, stream>>>(partF, nullptr, raw1, BSZ, 512, 16);
    bn_gelu_head<<<2, 256, 0, stream>>>(raw1, g6, be6, y1, BSZ, 512);
    fc_split<<<(BSZ * 256 * 8 + 255) / 256, 256, 0, stream>>>(y1, L2, partF, BSZ, 512, 256, 8);
    fc_reduce<<<(BSZ * 256 + 255) / 256, 256, 0, stream>>>(partF, bL2, raw2, BSZ, 256, 8);
    bn_gelu_head<<<1, 256, 0, stream>>>(raw2, g7, be7, y2, BSZ, 256);
    fc_split<<<(BSZ * 40 * 4 + 255) / 256, 256, 0, stream>>>(y2, L3, partF, BSZ, 256, 40, 4);
    fc_reduce<<<(BSZ * 40 + 255) / 256, 256, 0, stream>>>(partF, bL3, outp, BSZ, 40, 4);
}

// Round 7
// 1207.116 us; speedup vs baseline: 2.3852x; 1.0414x over previous
//
#include <hip/hip_runtime.h>
#include <hip/hip_bf16.h>
#include <cstddef>

#define BSZ 16
#define NPT 1024
#define KNN 30
#define TKR 9
#define FLT_BIG 3.402823466e+38f
#define DBL_BIG 1.0e300

__device__ __forceinline__ float gelu_f(float x) {
    return 0.5f * x * (1.0f + erff(x * 0.7071067811865476f));
}

// ---------------------------------------------------------------------------
// 1. transpose x [B,3,N] -> pts [B,N,3]
// ---------------------------------------------------------------------------
__global__ __launch_bounds__(256) void transpose_kernel(
    const float* __restrict__ x, float* __restrict__ pts) {
    int t = blockIdx.x * 256 + threadIdx.x;
    if (t >= BSZ * NPT) return;
    int b = t >> 10, n = t & 1023;
    const float* xp = x + (size_t)b * 3 * NPT;
    pts[t * 3 + 0] = xp[n];
    pts[t * 3 + 1] = xp[NPT + n];
    pts[t * 3 + 2] = xp[2 * NPT + n];
}

// ---------------------------------------------------------------------------
// 2. kNN, REGISTER-ONLY, 4 waves/block (no shared state, no barriers).
//    fp64 distances for exact top_k ordering vs the fp64 gold ref.
// ---------------------------------------------------------------------------
__global__ __launch_bounds__(256) void knn_kernel(
    const float* __restrict__ pts, int* __restrict__ idx) {
    int wave = threadIdx.x >> 6, lane = threadIdx.x & 63;
    int bn_ = blockIdx.x * 4 + wave;
    int b = bn_ >> 10;
    double px = (double)pts[(size_t)bn_ * 3 + 0];
    double py = (double)pts[(size_t)bn_ * 3 + 1];
    double pz = (double)pts[(size_t)bn_ * 3 + 2];
    double xn = px * px + py * py + pz * pz;
    const float* pb = pts + (size_t)(b << 10) * 3;
    int base = lane * 16;
    double cand[16];
    #pragma unroll
    for (int j = 0; j < 16; j++) {
        int m = base + j;
        double qx = (double)pb[m * 3 + 0];
        double qy = (double)pb[m * 3 + 1];
        double qz = (double)pb[m * 3 + 2];
        double inner = px * qx + py * qy + pz * qz;
        double xm = qx * qx + qy * qy + qz * qz;
        cand[j] = 2.0 * inner - xn - xm;
    }
    int* op = idx + (size_t)bn_ * KNN;
    for (int it = 0; it < KNN; it++) {
        double bv = -DBL_BIG;
        int bi = 0x7fffffff;
        #pragma unroll
        for (int j = 0; j < 16; j++) {
            if (cand[j] > bv) { bv = cand[j]; bi = base + j; }  // strict > : lowest idx
        }
        #pragma unroll
        for (int s = 1; s < 64; s <<= 1) {
            double ov = __shfl_xor(bv, s, 64);
            int oi = __shfl_xor(bi, s, 64);
            if (ov > bv || (ov == bv && oi < bi)) { bv = ov; bi = oi; }
        }
        if (lane == 0) op[it] = bi;
        #pragma unroll
        for (int j = 0; j < 16; j++) {
            if (base + j == bi) cand[j] = -DBL_BIG;   // register kill, exact
        }
    }
}

// ---------------------------------------------------------------------------
// 3. basis: Fourier feats -> sparsemax(w) -> P[k,t] per point. Block = 64.
// ---------------------------------------------------------------------------
__global__ __launch_bounds__(64) void basis_kernel(
    const float* __restrict__ pts, const int* __restrict__ idx,
    const float* __restrict__ B_ff, const float* __restrict__ mlp_W,
    const float* __restrict__ permx, float* __restrict__ P) {
    __shared__ float npt[KNN * 3];
    __shared__ float feats[7 * KNN];
    __shared__ float sc[64];
    __shared__ float zl[16];
    __shared__ float w[16];
    int bn_ = blockIdx.x;
    int b = bn_ >> 10;
    int tid = threadIdx.x;
    const int* ip = idx + (size_t)bn_ * KNN;
    if (tid < KNN) {
        int m = ip[tid];
        const float* q = pts + ((size_t)(b << 10) + m) * 3;
        npt[tid * 3 + 0] = q[0];
        npt[tid * 3 + 1] = q[1];
        npt[tid * 3 + 2] = q[2];
    }
    __syncthreads();
    if (tid < KNN) {
        float sx = npt[0], sy = npt[1], sz = npt[2];
        float rx = npt[tid * 3 + 0] - sx;
        float ry = npt[tid * 3 + 1] - sy;
        float rz = npt[tid * 3 + 2] - sz;
        float sq = rx * rx + ry * ry + rz * rz;
        float dist = (sq > 0.0f) ? sqrtf(sq) : 0.0f;
        feats[tid * 7 + 0] = sx;
        feats[tid * 7 + 1] = sy;
        feats[tid * 7 + 2] = sz;
        feats[tid * 7 + 3] = rx;
        feats[tid * 7 + 4] = ry;
        feats[tid * 7 + 5] = rz;
        feats[tid * 7 + 6] = dist;
    }
    __syncthreads();
    if (tid < 32) {
        float acc = 0.0f;
        for (int i = 0; i < 7 * KNN; i++) acc += feats[i] * B_ff[i * 32 + tid];
        float ffv = 6.283185307179586f * acc;
        sc[tid] = sinf(ffv);
        sc[tid + 32] = cosf(ffv);
    }
    __syncthreads();
    if (tid < 16) {
        float acc = 0.0f;
        for (int j = 0; j < 64; j++) acc += sc[j] * mlp_W[j * 16 + tid];
        zl[tid] = acc;
    }
    __syncthreads();
    if (tid == 0) {
        float zs[16];
        for (int i = 0; i < 16; i++) zs[i] = zl[i];
        for (int i = 1; i < 16; i++) {          // insertion sort descending
            float key = zs[i]; int j = i - 1;
            while (j >= 0 && zs[j] < key) { zs[j + 1] = zs[j]; j--; }
            zs[j + 1] = key;
        }
        float cs = 0.0f, csarr[16];
        int cnt = 0;
        for (int j = 0; j < 16; j++) {
            cs += zs[j];
            csarr[j] = cs;
            if (1.0f + (float)(j + 1) * zs[j] > cs) cnt++;
        }
        float tau = (csarr[cnt - 1] - 1.0f) / (float)cnt;
        for (int i = 0; i < 16; i++) w[i] = fmaxf(zl[i] - tau, 0.0f);
    }
    __syncthreads();
    float* Pp = P + (size_t)bn_ * (KNN * TKR);
    for (int e = tid; e < KNN * TKR; e += 64) {
        int k = e / TKR, t = e - TKR * k;
        float acc = 0.0f;
        for (int i = 0; i < 16; i++) acc += w[i] * permx[(i * KNN + k) * TKR + t];
        Pp[e] = acc;
    }
}

// ---------------------------------------------------------------------------
// 4a. agg: Z[bn, t*CIN+c] = sum_k nb[k,c]*P[k,t]; Z[bn, 9*CIN+c] = self[c];
//     zero-pad to kpad. One block per point.
// ---------------------------------------------------------------------------
template <int CIN>
__global__ __launch_bounds__(256) void agg_kernel(
    const float* __restrict__ ft, int ftst,
    const float* __restrict__ P, const int* __restrict__ idx,
    float* __restrict__ Z, int kpad) {
    __shared__ float sP[KNN * TKR];
    __shared__ float sNb[KNN * CIN];
    __shared__ int sIdx[KNN];
    int bn_ = blockIdx.x;
    int b = bn_ >> 10;
    int tid = threadIdx.x;
    if (tid < KNN) sIdx[tid] = idx[(size_t)bn_ * KNN + tid];
    for (int e = tid; e < KNN * TKR; e += 256) sP[e] = P[(size_t)bn_ * (KNN * TKR) + e];
    __syncthreads();
    for (int e = tid; e < KNN * CIN; e += 256) {
        int k = e / CIN, c = e - k * CIN;
        sNb[e] = ft[((size_t)(b << 10) + sIdx[k]) * ftst + c];
    }
    __syncthreads();
    float* zp = Z + (size_t)bn_ * kpad;
    const int KW = TKR * CIN;
    for (int e = tid; e < kpad; e += 256) {
        float v;
        if (e < KW) {
            int t = e / CIN, c = e - t * CIN;
            float acc = 0.0f;
            #pragma unroll
            for (int k = 0; k < KNN; k++) acc += sNb[k * CIN + c] * sP[k * TKR + t];
            v = acc;
        } else if (e < KW + CIN) {
            v = ft[(size_t)bn_ * ftst + (e - KW)];
        } else {
            v = 0.0f;
        }
        zp[e] = v;
    }
}

// ---------------------------------------------------------------------------
// 4b. prep WZ = [W ; S ; 0-pad]  (kpad x N)
// ---------------------------------------------------------------------------
__global__ __launch_bounds__(256) void prep_wz(
    const float* __restrict__ W, const float* __restrict__ S,
    float* __restrict__ WZ, int KW, int KS, int N, int kpad) {
    int t = blockIdx.x * 256 + threadIdx.x;
    if (t >= kpad * N) return;
    int k = t / N, n = t - k * N;
    float v = 0.0f;
    if (k < KW) v = W[(size_t)k * N + n];
    else if (k < KW + KS) v = S[(size_t)(k - KW) * N + n];
    WZ[t] = v;
}

// ---------------------------------------------------------------------------
// 5a. conv5 GEMM (proven R5 config): 128x128 tile, 2-barrier, NO reg
//     prefetch — 64 VGPR keeps ~30% occupancy (prefetch variant hit the
//     128-VGPR cliff: occ 30%->11%, 207->268 us. measured R6).
// ---------------------------------------------------------------------------
template <bool GELU, bool HASBIAS>
__global__ __launch_bounds__(256) void gemm_f32_128(
    const float* __restrict__ A, int lda,
    const float* __restrict__ B, int ldb, int K,
    const float* __restrict__ bias,
    float* __restrict__ C, int ldc) {
    __shared__ float As[16][128];
    __shared__ float Bs[16][128];
    int tid = threadIdx.x;
    int tx = tid & 15, ty = tid >> 4;
    int m0 = blockIdx.y * 128, n0 = blockIdx.x * 128;
    float acc[8][8];
    #pragma unroll
    for (int i = 0; i < 8; i++)
        #pragma unroll
        for (int j = 0; j < 8; j++) acc[i][j] = 0.0f;

    int ar = tid >> 1, ac0 = (tid & 1) * 8;
    const float* aptr = A + (size_t)(m0 + ar) * lda + ac0;

    for (int k0 = 0; k0 < K; k0 += 16) {
        float4 a0 = *(const float4*)(aptr + k0);
        float4 a1 = *(const float4*)(aptr + k0 + 4);
        As[ac0 + 0][ar] = a0.x; As[ac0 + 1][ar] = a0.y;
        As[ac0 + 2][ar] = a0.z; As[ac0 + 3][ar] = a0.w;
        As[ac0 + 4][ar] = a1.x; As[ac0 + 5][ar] = a1.y;
        As[ac0 + 6][ar] = a1.z; As[ac0 + 7][ar] = a1.w;
        {
            int r = tid >> 5, c = (tid & 31) * 4;
            const float* bp = B + (size_t)(k0 + r) * ldb + n0 + c;
            float4 b0 = *(const float4*)bp;
            float4 b1 = *(const float4*)(bp + (size_t)8 * ldb);
            *(float4*)&Bs[r][c] = b0;
            *(float4*)&Bs[r + 8][c] = b1;
        }
        __syncthreads();
        #pragma unroll
        for (int kk = 0; kk < 16; kk++) {
            float av[8], bv[8];
            *(float4*)&av[0] = *(const float4*)&As[kk][ty * 4];
            *(float4*)&av[4] = *(const float4*)&As[kk][64 + ty * 4];
            *(float4*)&bv[0] = *(const float4*)&Bs[kk][tx * 4];
            *(float4*)&bv[4] = *(const float4*)&Bs[kk][64 + tx * 4];
            #pragma unroll
            for (int i = 0; i < 8; i++)
                #pragma unroll
                for (int j = 0; j < 8; j++) acc[i][j] += av[i] * bv[j];
        }
        __syncthreads();
    }
    #pragma unroll
    for (int hi = 0; hi < 2; hi++) {
        #pragma unroll
        for (int i = 0; i < 4; i++) {
            int r = m0 + hi * 64 + ty * 4 + i;
            #pragma unroll
            for (int hj = 0; hj < 2; hj++) {
                int c = n0 + hj * 64 + tx * 4;
                float v[4];
                #pragma unroll
                for (int j = 0; j < 4; j++) {
                    float t = acc[hi * 4 + i][hj * 4 + j];
                    if (HASBIAS) t += bias[c + j];
                    if (GELU) t = gelu_f(t);
                    v[j] = t;
                }
                *(float4*)(C + (size_t)r * ldc + c) = *(float4*)v;
            }
        }
    }
}

// ---------------------------------------------------------------------------
// 5b. 64x64 GEMM, LDS double-buffered + reg prefetch, ONE barrier per
//     K-iter. acc is only 16 VGPR so prefetch regs (8) stay under the
//     occupancy cliff. Accumulation order identical to the simple version.
// ---------------------------------------------------------------------------
template <bool GELU, bool HASBIAS>
__global__ __launch_bounds__(256) void gemm_f32_64db(
    const float* __restrict__ A, int lda,
    const float* __restrict__ B, int ldb, int K,
    const float* __restrict__ bias,
    float* __restrict__ C, int ldc) {
    __shared__ float As[2][16][64];
    __shared__ float Bs[2][16][64];
    int tid = threadIdx.x;
    int tx = tid & 15, ty = tid >> 4;
    int m0 = blockIdx.y * 64, n0 = blockIdx.x * 64;
    float acc[4][4];
    #pragma unroll
    for (int i = 0; i < 4; i++)
        #pragma unroll
        for (int j = 0; j < 4; j++) acc[i][j] = 0.0f;

    int ar = tid >> 2, ac0 = (tid & 3) * 4;
    const float* aptr = A + (size_t)(m0 + ar) * lda + ac0;
    int br = tid >> 4, bc = (tid & 15) * 4;
    const float* bptr = B + (size_t)br * ldb + n0 + bc;

    // prologue: tile 0 -> LDS[0]
    float4 pa = *(const float4*)(aptr);
    float4 pb = *(const float4*)(bptr);
    As[0][ac0 + 0][ar] = pa.x; As[0][ac0 + 1][ar] = pa.y;
    As[0][ac0 + 2][ar] = pa.z; As[0][ac0 + 3][ar] = pa.w;
    *(float4*)&Bs[0][br][bc] = pb;
    __syncthreads();

    int nk = K >> 4;
    for (int t = 0; t < nk; t++) {
        int buf = t & 1;
        bool more = (t + 1) < nk;
        if (more) {   // global loads in flight across the whole compute phase
            int k0 = (t + 1) << 4;
            pa = *(const float4*)(aptr + k0);
            pb = *(const float4*)(bptr + (size_t)k0 * ldb);
        }
        #pragma unroll
        for (int kk = 0; kk < 16; kk++) {
            float av[4], bv[4];
            *(float4*)&av[0] = *(const float4*)&As[buf][kk][ty * 4];
            *(float4*)&bv[0] = *(const float4*)&Bs[buf][kk][tx * 4];
            #pragma unroll
            for (int i = 0; i < 4; i++)
                #pragma unroll
                for (int j = 0; j < 4; j++) acc[i][j] += av[i] * bv[j];
        }
        if (more) {
            int nb = 1 - buf;
            As[nb][ac0 + 0][ar] = pa.x; As[nb][ac0 + 1][ar] = pa.y;
            As[nb][ac0 + 2][ar] = pa.z; As[nb][ac0 + 3][ar] = pa.w;
            *(float4*)&Bs[nb][br][bc] = pb;
        }
        __syncthreads();
    }
    #pragma unroll
    for (int i = 0; i < 4; i++) {
        int r = m0 + ty * 4 + i;
        int c = n0 + tx * 4;
        float v[4];
        #pragma unroll
        for (int j = 0; j < 4; j++) {
            float t = acc[i][j];
            if (HASBIAS) t += bias[c + j];
            if (GELU) t = gelu_f(t);
            v[j] = t;
        }
        *(float4*)(C + (size_t)r * ldc + c) = *(float4*)v;
    }
}

// ---------------------------------------------------------------------------
// 6. BN stats, two-stage deterministic (NO atomics, NO memset).
// ---------------------------------------------------------------------------
__global__ __launch_bounds__(256) void stats_partial(
    const float* __restrict__ f5, double* __restrict__ partS,
    double* __restrict__ partQ) {
    int tid = threadIdx.x;
    double s[4] = {0.0, 0.0, 0.0, 0.0};
    double q[4] = {0.0, 0.0, 0.0, 0.0};
    int p0 = blockIdx.x * 64;
    for (int p = p0; p < p0 + 64; p++) {
        const float* row = f5 + (size_t)p * 1024;
        #pragma unroll
        for (int k = 0; k < 4; k++) {
            double v = (double)row[tid + 256 * k];
            s[k] += v;
            q[k] += v * v;
        }
    }
    #pragma unroll
    for (int k = 0; k < 4; k++) {
        partS[(size_t)blockIdx.x * 1024 + tid + 256 * k] = s[k];
        partQ[(size_t)blockIdx.x * 1024 + tid + 256 * k] = q[k];
    }
}

__global__ __launch_bounds__(256) void stats_reduce(
    const double* __restrict__ partS, const double* __restrict__ partQ,
    const float* __restrict__ g, const float* __restrict__ be,
    float* __restrict__ scaleb, float* __restrict__ shiftb) {
    int e = blockIdx.x * 256 + threadIdx.x;
    if (e >= 1024) return;
    double s = 0.0, q = 0.0;
    for (int b = 0; b < 256; b++) {
        s += partS[(size_t)b * 1024 + e];
        q += partQ[(size_t)b * 1024 + e];
    }
    double m = s * (1.0 / 16384.0);
    double v = q * (1.0 / 16384.0) - m * m;
    float sc = g[e] * (float)(1.0 / sqrt(v + 1e-5));
    scaleb[e] = sc;
    shiftb[e] = be[e] - (float)m * sc;
}

// ---------------------------------------------------------------------------
// 7. pool: h[b, 0:1024] = max_n gelu(bn(f5)); h[b,1024:2048] = mean_n
// ---------------------------------------------------------------------------
__global__ __launch_bounds__(256) void pool_kernel(
    const float* __restrict__ f5, const float* __restrict__ scaleb,
    const float* __restrict__ shiftb, float* __restrict__ h) {
    int b = blockIdx.x >> 4;
    int g = blockIdx.x & 15;
    int e = g * 64 + (threadIdx.x & 63);
    int nlane = threadIdx.x >> 6;
    float sc = scaleb[e], sh = shiftb[e];
    float vmax = -FLT_BIG;
    double vsum = 0.0;
    for (int n = nlane; n < NPT; n += 4) {
        float v = f5[((size_t)b * NPT + n) * 1024 + e];
        v = gelu_f(v * sc + sh);
        vmax = fmaxf(vmax, v);
        vsum += (double)v;
    }
    __shared__ float smax[256];
    __shared__ double ssum[256];
    smax[threadIdx.x] = vmax;
    ssum[threadIdx.x] = vsum;
    __syncthreads();
    if (nlane == 0) {
        for (int i = 1; i < 4; i++) {
            vmax = fmaxf(vmax, smax[threadIdx.x + 64 * i]);
            vsum += ssum[threadIdx.x + 64 * i];
        }
        h[(size_t)b * 2048 + e] = vmax;
        h[(size_t)b * 2048 + 1024 + e] = (float)(vsum * (1.0 / 1024.0));
    }
}

// ---------------------------------------------------------------------------
// 8. FC head, split-K (fp64, deterministic).
// ---------------------------------------------------------------------------
__global__ __launch_bounds__(256) void fc_split(
    const float* __restrict__ X, const float* __restrict__ W,
    double* __restrict__ part, int Bn, int In, int Out, int KC) {
    int tid = blockIdx.x * 256 + threadIdx.x;
    if (tid >= Bn * Out * KC) return;
    int chunk = tid / (Bn * Out);
    int r = tid - chunk * (Bn * Out);
    int b = r / Out, j = r - b * Out;
    int len = In / KC;
    int i0 = chunk * len;
    const float* x = X + (size_t)b * In + i0;
    const float* w = W + (size_t)i0 * Out + j;
    double acc = 0.0;
    for (int i = 0; i < len; i++) acc += (double)x[i] * (double)w[(size_t)i * Out];
    part[tid] = acc;
}

__global__ __launch_bounds__(256) void fc_reduce(
    const double* __restrict__ part, const float* __restrict__ bias,
    float* __restrict__ Y, int Bn, int Out, int KC) {
    int r = blockIdx.x * 256 + threadIdx.x;
    if (r >= Bn * Out) return;
    int j = r % Out;
    double acc = bias ? (double)bias[j] : 0.0;
    for (int c = 0; c < KC; c++) acc += part[(size_t)c * (Bn * Out) + r];
    Y[r] = (float)acc;
}

__global__ __launch_bounds__(256) void bn_gelu_head(
    const float* __restrict__ Xraw, const float* __restrict__ g,
    const float* __restrict__ be, float* __restrict__ Y, int Bn, int F) {
    int j = blockIdx.x * 256 + threadIdx.x;
    if (j >= F) return;
    double m = 0.0;
    for (int b = 0; b < Bn; b++) m += (double)Xraw[b * F + j];
    m /= (double)Bn;
    double v = 0.0;
    for (int b = 0; b < Bn; b++) {
        double dd = (double)Xraw[b * F + j] - m;
        v += dd * dd;
    }
    v /= (double)Bn;
    float sc = g[j] * (float)(1.0 / sqrt(v + 1e-5));
    float sh = be[j] - (float)m * sc;
    for (int b = 0; b < Bn; b++) Y[b * F + j] = gelu_f(Xraw[b * F + j] * sc + sh);
}

// ---------------------------------------------------------------------------
extern "C" void kernel_launch(void* const* d_in, const int* in_sizes, int n_in,
                              void* d_out, int out_size, void* d_ws, size_t ws_size,
                              hipStream_t stream) {
    const float* x     = (const float*)d_in[0];
    const float* B_ff  = (const float*)d_in[1];
    const float* mlp_W = (const float*)d_in[2];
    const float* permx = (const float*)d_in[3];
    const float* W1 = (const float*)d_in[4];
    const float* b1 = (const float*)d_in[5];
    const float* S1 = (const float*)d_in[6];
    const float* W2 = (const float*)d_in[7];
    const float* b2 = (const float*)d_in[8];
    const float* S2 = (const float*)d_in[9];
    const float* W3 = (const float*)d_in[10];
    const float* b3 = (const float*)d_in[11];
    const float* S3 = (const float*)d_in[12];
    const float* W4 = (const float*)d_in[13];
    const float* b4 = (const float*)d_in[14];
    const float* S4 = (const float*)d_in[15];
    const float* W5 = (const float*)d_in[16];
    const float* g5 = (const float*)d_in[17];
    const float* be5 = (const float*)d_in[18];
    const float* L1 = (const float*)d_in[19];
    const float* g6 = (const float*)d_in[20];
    const float* be6 = (const float*)d_in[21];
    const float* L2 = (const float*)d_in[22];
    const float* bL2 = (const float*)d_in[23];
    const float* g7 = (const float*)d_in[24];
    const float* be7 = (const float*)d_in[25];
    const float* L3 = (const float*)d_in[26];
    const float* bL3 = (const float*)d_in[27];
    float* outp = (float*)d_out;

    const int BN = BSZ * NPT;  // 16384

    // workspace layout (float units; 16B-aligned). Unions:
    //   f5 aliases Zbig (Zbig dead after L4 GEMM);
    //   partS/partQ/partF alias Pb (Pb dead after L4 agg; 5 MB << 17.7 MB).
    float* ws = (float*)d_ws;
    float* pts   = ws;                         // 49152
    int*   idxb  = (int*)(ws + 49152);         // 491520 ints
    float* Pb    = ws + 540672;                // 4423680
    float* feat  = Pb + 4423680;               // 8388608 (x1|x2|x3|x4, stride 512)
    float* Zbig  = feat + 8388608;             // 20971520 (max layer: 16384x1280)
    float* f5    = Zbig;                       // union: 16777216
    float* WZ    = Zbig + 20971520;            // 327680 (max 1280x256)
    float* scb   = WZ + 327680;                // 1024
    float* shb   = scb + 1024;                 // 1024
    float* hb    = shb + 1024;                 // 32768
    float* raw1  = hb + 32768;                 // 8192
    float* y1    = raw1 + 8192;                // 8192
    float* raw2  = y1 + 8192;                  // 4096
    float* y2    = raw2 + 4096;                // 4096
    double* partS = (double*)Pb;               // union: 262144 doubles
    double* partQ = partS + 262144;            // 262144 doubles
    double* partF = partQ + 262144;            // 131072 doubles (max FC partials)
    size_t need_bytes = (size_t)((y2 + 4096) - ws) * sizeof(float);
    if (ws_size < need_bytes) return;

    transpose_kernel<<<(BN + 255) / 256, 256, 0, stream>>>(x, pts);
    knn_kernel<<<BN / 4, 256, 0, stream>>>(pts, idxb);
    basis_kernel<<<BN, 64, 0, stream>>>(pts, idxb, B_ff, mlp_W, permx, Pb);

    // ---- layer 1: CIN=3, K=27+3=30 pad 32, N=64 ----
    prep_wz<<<(32 * 64 + 255) / 256, 256, 0, stream>>>(W1, S1, WZ, 27, 3, 64, 32);
    agg_kernel<3><<<BN, 256, 0, stream>>>(pts, 3, Pb, idxb, Zbig, 32);
    gemm_f32_64db<true, true><<<dim3(1, 256), 256, 0, stream>>>(
        Zbig, 32, WZ, 64, 32, b1, feat + 0, 512);
    // ---- layer 2: CIN=64, K=576+64=640, N=64 ----
    prep_wz<<<(640 * 64 + 255) / 256, 256, 0, stream>>>(W2, S2, WZ, 576, 64, 64, 640);
    agg_kernel<64><<<BN, 256, 0, stream>>>(feat + 0, 512, Pb, idxb, Zbig, 640);
    gemm_f32_64db<true, true><<<dim3(1, 256), 256, 0, stream>>>(
        Zbig, 640, WZ, 64, 640, b2, feat + 64, 512);
    // ---- layer 3: CIN=64, K=640, N=128 ----
    prep_wz<<<(640 * 128 + 255) / 256, 256, 0, stream>>>(W3, S3, WZ, 576, 64, 128, 640);
    agg_kernel<64><<<BN, 256, 0, stream>>>(feat + 64, 512, Pb, idxb, Zbig, 640);
    gemm_f32_64db<true, true><<<dim3(2, 256), 256, 0, stream>>>(
        Zbig, 640, WZ, 128, 640, b3, feat + 128, 512);
    // ---- layer 4: CIN=128, K=1152+128=1280, N=256 ----
    prep_wz<<<(1280 * 256 + 255) / 256, 256, 0, stream>>>(W4, S4, WZ, 1152, 128, 256, 1280);
    agg_kernel<128><<<BN, 256, 0, stream>>>(feat + 128, 512, Pb, idxb, Zbig, 1280);
    gemm_f32_64db<true, true><<<dim3(4, 256), 256, 0, stream>>>(
        Zbig, 1280, WZ, 256, 1280, b4, feat + 256, 512);

    // ---- conv5: f5[BN,1024] = feat[BN,512] @ W5 (Zbig dead -> f5 reuses it) ----
    gemm_f32_128<false, false><<<dim3(8, 128), 256, 0, stream>>>(
        feat, 512, W5, 1024, 512, nullptr, f5, 1024);

    // ---- BN stats (deterministic 2-stage; partials alias dead Pb) ----
    stats_partial<<<256, 256, 0, stream>>>(f5, partS, partQ);
    stats_reduce<<<4, 256, 0, stream>>>(partS, partQ, g5, be5, scb, shb);
    pool_kernel<<<BSZ * 16, 256, 0, stream>>>(f5, scb, shb, hb);

    // ---- FC head, split-K fp64 ----
    fc_split<<<(BSZ * 512 * 16 + 255) / 256, 256, 0, stream>>>(hb, L1, partF, BSZ, 2048, 512, 16);
    fc_reduce<<<(BSZ * 512 + 255) / 256, 256, 0, stream>>>(partF, nullptr, raw1, BSZ, 512, 16);
    bn_gelu_head<<<2, 256, 0, stream>>>(raw1, g6, be6, y1, BSZ, 512);
    fc_split<<<(BSZ * 256 * 8 + 255) / 256, 256, 0, stream>>>(y1, L2, partF, BSZ, 512, 256, 8);
    fc_reduce<<<(BSZ * 256 + 255) / 256, 256, 0, stream>>>(partF, bL2, raw2, BSZ, 256, 8);
    bn_gelu_head<<<1, 256, 0, stream>>>(raw2, g7, be7, y2, BSZ, 256);
    fc_split<<<(BSZ * 40 * 4 + 255) / 256, 256, 0, stream>>>(y2, L3, partF, BSZ, 256, 40, 4);
    fc_reduce<<<(BSZ * 40 + 255) / 256, 256, 0, stream>>>(partF, bL3, outp, BSZ, 40, 4);
}